// Round 1
// baseline (406.097 us; speedup 1.0000x reference)
//
#include <hip/hip_runtime.h>
#include <hip/hip_bf16.h>

using bf16 = __hip_bfloat16;
typedef __attribute__((ext_vector_type(4))) float f32x4;
typedef __attribute__((ext_vector_type(8))) short bf16x8;

#define NPX 4096
#define CCH 512

__device__ __forceinline__ void async16(const bf16* g, bf16* l) {
  __builtin_amdgcn_global_load_lds((const __attribute__((address_space(1))) void*)g,
                                   (__attribute__((address_space(3))) void*)l, 16, 0, 0);
}

__device__ __forceinline__ float bfb2f(short s) {
  unsigned u = ((unsigned)(unsigned short)s) << 16;
  float f;
  __builtin_memcpy(&f, &u, 4);
  return f;
}

__device__ __forceinline__ short f2bfb(float f) {
  bf16 h = __float2bfloat16(f);
  short s;
  __builtin_memcpy(&s, &h, 2);
  return s;
}

// ---------------- fp32 -> bf16 convert ----------------
__global__ __launch_bounds__(256) void f32_to_bf16_kernel(const float* __restrict__ in,
                                                          bf16* __restrict__ out, int n) {
  int i = (blockIdx.x * 256 + threadIdx.x) * 4;
  if (i + 3 < n) {
    float4 v = *reinterpret_cast<const float4*>(in + i);
    out[i]     = __float2bfloat16(v.x);
    out[i + 1] = __float2bfloat16(v.y);
    out[i + 2] = __float2bfloat16(v.z);
    out[i + 3] = __float2bfloat16(v.w);
  }
}

// ---------------- GroupNorm stats: one block per (b,g) ----------------
__global__ __launch_bounds__(256) void gn_stats_kernel(const float* __restrict__ x,
                                                       float* __restrict__ stats) {
  // group g of batch b covers 16 channels * 4096 px = 65536 contiguous floats
  const float* p = x + (size_t)blockIdx.x * 65536;
  float s = 0.f, s2 = 0.f;
  int t = threadIdx.x;
  for (int i = t * 4; i < 65536; i += 256 * 4) {
    float4 v = *reinterpret_cast<const float4*>(p + i);
    s  += v.x + v.y + v.z + v.w;
    s2 += v.x * v.x + v.y * v.y + v.z * v.z + v.w * v.w;
  }
  #pragma unroll
  for (int off = 32; off >= 1; off >>= 1) {
    s  += __shfl_xor(s, off);
    s2 += __shfl_xor(s2, off);
  }
  __shared__ float ls[8];
  int wv = t >> 6;
  if ((t & 63) == 0) { ls[wv * 2] = s; ls[wv * 2 + 1] = s2; }
  __syncthreads();
  if (t == 0) {
    float S  = ls[0] + ls[2] + ls[4] + ls[6];
    float S2 = ls[1] + ls[3] + ls[5] + ls[7];
    float mean = S * (1.f / 65536.f);
    float var  = S2 * (1.f / 65536.f) - mean * mean;
    stats[blockIdx.x * 2]     = mean;
    stats[blockIdx.x * 2 + 1] = rsqrtf(var + 1e-6f);
  }
}

// ---------------- GroupNorm apply + transpose to [n][c] bf16 ----------------
__global__ __launch_bounds__(256) void gn_apply_kernel(const float* __restrict__ x,
    const float* __restrict__ stats, const float* __restrict__ gamma,
    const float* __restrict__ beta, bf16* __restrict__ h) {
  __shared__ float tile[64][65];
  int b  = blockIdx.z;
  int c0 = blockIdx.x * 64, n0 = blockIdx.y * 64;
  int t  = threadIdx.x;
  int cl = t >> 6, nl = t & 63;
  #pragma unroll
  for (int i = 0; i < 16; i++) {
    int c = c0 + cl + i * 4;
    float v = x[((size_t)b * CCH + c) * NPX + n0 + nl];
    int g = c >> 4;  // 16 channels per group
    float mean = stats[(b * 32 + g) * 2];
    float rstd = stats[(b * 32 + g) * 2 + 1];
    tile[cl + i * 4][nl] = (v - mean) * rstd * gamma[c] + beta[c];
  }
  __syncthreads();
  #pragma unroll
  for (int i = 0; i < 16; i++) {
    int n = cl + i * 4;
    int c = nl;
    h[((size_t)b * NPX + n0 + n) * CCH + c0 + c] = __float2bfloat16(tile[c][n]);
  }
}

// ---------------- B^T GEMM: C[m][n] = alpha * sum_k A[m][k] B[n][k] (+biases/resid)
// 128x128 tile, BK=64, 4 waves (2x2), 64x64 per wave, 16x16x32 bf16 MFMA.
// LDS XOR-swizzled via pre-swizzled global source (linear global_load_lds dest).
template<bool OUT_BF16>
__global__ __launch_bounds__(256, 2) void gemm_bt_kernel(
    const bf16* __restrict__ A, const bf16* __restrict__ B, void* __restrict__ C,
    const float* __restrict__ bias_m, const float* __restrict__ bias_n,
    const float* __restrict__ resid, float alpha, int K,
    int lda, int ldb, int ldc,
    long long sA, long long sB, long long sC, long long sR) {
  int bz = blockIdx.z;
  A += (size_t)bz * sA;
  B += (size_t)bz * sB;
  const int m0 = blockIdx.x * 128, n0 = blockIdx.y * 128;

  __shared__ bf16 ldsA[128 * 64];
  __shared__ bf16 ldsB[128 * 64];

  const int t = threadIdx.x;
  const int lane = t & 63, wv = t >> 6;
  const int wr = (wv >> 1) * 64, wc = (wv & 1) * 64;

  // staging: thread t loads 16B chunks; dest linear byte = t*16 + i*4096
  const int r0 = t >> 3;                              // tile row 0..31 (+32i)
  const int cb = ((t & 7) << 4) ^ ((r0 & 7) << 4);    // pre-swizzled source col byte
  const bf16* gA = A + (size_t)(m0 + r0) * lda + (cb >> 1);
  const bf16* gB = B + (size_t)(n0 + r0) * ldb + (cb >> 1);
  bf16* lA = ldsA + t * 8;
  bf16* lB = ldsB + t * 8;

  const int arow = wr + (lane & 15);
  const int brow = wc + (lane & 15);
  const int kb   = (lane >> 4) * 16;  // byte offset of this lane's 8 k-elems

  f32x4 acc[4][4] = {};

  for (int k0 = 0; k0 < K; k0 += 64) {
    #pragma unroll
    for (int i = 0; i < 4; i++) {
      async16(gA + (size_t)i * 32 * lda + k0, lA + i * 2048);
      async16(gB + (size_t)i * 32 * ldb + k0, lB + i * 2048);
    }
    __syncthreads();
    #pragma unroll
    for (int ks = 0; ks < 2; ks++) {
      bf16x8 af[4], bfr[4];
      #pragma unroll
      for (int f = 0; f < 4; f++) {
        int ra = arow + f * 16;
        af[f] = *reinterpret_cast<const bf16x8*>(
            reinterpret_cast<const char*>(ldsA) + ra * 128 + ((ks * 64 + kb) ^ ((ra & 7) << 4)));
        int rb = brow + f * 16;
        bfr[f] = *reinterpret_cast<const bf16x8*>(
            reinterpret_cast<const char*>(ldsB) + rb * 128 + ((ks * 64 + kb) ^ ((rb & 7) << 4)));
      }
      #pragma unroll
      for (int fm = 0; fm < 4; fm++)
        #pragma unroll
        for (int fn = 0; fn < 4; fn++)
          acc[fm][fn] = __builtin_amdgcn_mfma_f32_16x16x32_bf16(af[fm], bfr[fn], acc[fm][fn], 0, 0, 0);
    }
    __syncthreads();
  }

  #pragma unroll
  for (int fm = 0; fm < 4; fm++) {
    #pragma unroll
    for (int j = 0; j < 4; j++) {
      int gm = m0 + wr + fm * 16 + (lane >> 4) * 4 + j;
      float bm = bias_m ? bias_m[gm] : 0.f;
      #pragma unroll
      for (int fn = 0; fn < 4; fn++) {
        int gn = n0 + wc + fn * 16 + (lane & 15);
        float vv = acc[fm][fn][j] * alpha + bm;
        if (bias_n) vv += bias_n[gn];
        if (resid)  vv += resid[(size_t)bz * sR + (size_t)gm * ldc + gn];
        if (OUT_BF16)
          reinterpret_cast<bf16*>(C)[(size_t)bz * sC + (size_t)gm * ldc + gn] = __float2bfloat16(vv);
        else
          reinterpret_cast<float*>(C)[(size_t)bz * sC + (size_t)gm * ldc + gn] = vv;
      }
    }
  }
}

// ---------------- row softmax, in place on bf16 [4096] rows ----------------
__global__ __launch_bounds__(256) void softmax_kernel(bf16* __restrict__ S) {
  bf16* p = S + (size_t)blockIdx.x * NPX;
  int t = threadIdx.x;
  bf16x8 r0 = *reinterpret_cast<const bf16x8*>(p + t * 8);
  bf16x8 r1 = *reinterpret_cast<const bf16x8*>(p + 2048 + t * 8);
  float v[16];
  #pragma unroll
  for (int i = 0; i < 8; i++) {
    v[i]     = bfb2f(r0[i]);
    v[i + 8] = bfb2f(r1[i]);
  }
  float mx = -3e38f;
  #pragma unroll
  for (int i = 0; i < 16; i++) mx = fmaxf(mx, v[i]);
  #pragma unroll
  for (int off = 32; off >= 1; off >>= 1) mx = fmaxf(mx, __shfl_xor(mx, off));
  __shared__ float lsm[4];
  if ((t & 63) == 0) lsm[t >> 6] = mx;
  __syncthreads();
  mx = fmaxf(fmaxf(lsm[0], lsm[1]), fmaxf(lsm[2], lsm[3]));
  float sum = 0.f;
  #pragma unroll
  for (int i = 0; i < 16; i++) {
    v[i] = __expf(v[i] - mx);
    sum += v[i];
  }
  #pragma unroll
  for (int off = 32; off >= 1; off >>= 1) sum += __shfl_xor(sum, off);
  __shared__ float lss[4];
  if ((t & 63) == 0) lss[t >> 6] = sum;
  __syncthreads();
  sum = lss[0] + lss[1] + lss[2] + lss[3];
  float inv = 1.f / sum;
  bf16x8 o0, o1;
  #pragma unroll
  for (int i = 0; i < 8; i++) {
    o0[i] = f2bfb(v[i] * inv);
    o1[i] = f2bfb(v[i + 8] * inv);
  }
  *reinterpret_cast<bf16x8*>(p + t * 8) = o0;
  *reinterpret_cast<bf16x8*>(p + 2048 + t * 8) = o1;
}

extern "C" void kernel_launch(void* const* d_in, const int* in_sizes, int n_in,
                              void* d_out, int out_size, void* d_ws, size_t ws_size,
                              hipStream_t stream) {
  const float* x     = (const float*)d_in[0];
  const float* gamma = (const float*)d_in[1];
  const float* beta  = (const float*)d_in[2];
  const float* wq    = (const float*)d_in[3];
  const float* bq    = (const float*)d_in[4];
  const float* wk    = (const float*)d_in[5];
  const float* bk    = (const float*)d_in[6];
  const float* wv    = (const float*)d_in[7];
  const float* bv    = (const float*)d_in[8];
  const float* wp    = (const float*)d_in[9];
  const float* bp    = (const float*)d_in[10];
  float* out = (float*)d_out;

  char* w = (char*)d_ws;
  size_t off = 0;
  float* stats = (float*)w;            off += 1024;
  bf16* wqb = (bf16*)(w + off);        off += 512 * 512 * 2;
  bf16* wkb = (bf16*)(w + off);        off += 512 * 512 * 2;
  bf16* wvb = (bf16*)(w + off);        off += 512 * 512 * 2;
  bf16* wpb = (bf16*)(w + off);        off += 512 * 512 * 2;
  bf16* h   = (bf16*)(w + off);        off += (size_t)2 * NPX * CCH * 2;
  bf16* q   = (bf16*)(w + off);        off += (size_t)2 * NPX * CCH * 2;
  bf16* k   = (bf16*)(w + off);        off += (size_t)2 * NPX * CCH * 2;
  bf16* v   = (bf16*)(w + off);        off += (size_t)2 * NPX * CCH * 2;
  bf16* o   = (bf16*)(w + off);        off += (size_t)2 * NPX * CCH * 2;
  bf16* S   = (bf16*)(w + off);        off += (size_t)NPX * NPX * 2;

  const long long sBN = (long long)NPX * CCH;  // per-batch stride (elements)

  f32_to_bf16_kernel<<<256, 256, 0, stream>>>(wq, wqb, 262144);
  f32_to_bf16_kernel<<<256, 256, 0, stream>>>(wk, wkb, 262144);
  f32_to_bf16_kernel<<<256, 256, 0, stream>>>(wv, wvb, 262144);
  f32_to_bf16_kernel<<<256, 256, 0, stream>>>(wp, wpb, 262144);

  gn_stats_kernel<<<64, 256, 0, stream>>>(x, stats);
  gn_apply_kernel<<<dim3(8, 64, 2), 256, 0, stream>>>(x, stats, gamma, beta, h);

  // q_t[n][o] = sum_c h[n][c] wq[o][c] + bq[o]   (M=4096, N=512)
  gemm_bt_kernel<true><<<dim3(32, 4, 2), 256, 0, stream>>>(h, wqb, q, nullptr, bq, nullptr,
      1.f, 512, 512, 512, 512, sBN, 0, sBN, 0);
  gemm_bt_kernel<true><<<dim3(32, 4, 2), 256, 0, stream>>>(h, wkb, k, nullptr, bk, nullptr,
      1.f, 512, 512, 512, 512, sBN, 0, sBN, 0);
  // v[oc][n] = sum_c wv[oc][c] h[n][c] + bv[oc]  (M=512, N=4096)
  gemm_bt_kernel<true><<<dim3(4, 32, 2), 256, 0, stream>>>(wvb, h, v, bv, nullptr, nullptr,
      1.f, 512, 512, 512, 4096, 0, sBN, sBN, 0);

  const float scale = 0.04419417382415922f;  // 512^-0.5
  for (int b = 0; b < 2; b++) {
    // S[i][j] = scale * sum_c q[i][c] k[j][c]   (M=N=4096)
    gemm_bt_kernel<true><<<dim3(32, 32, 1), 256, 0, stream>>>(q + b * sBN, k + b * sBN, S,
        nullptr, nullptr, nullptr, scale, 512, 512, 512, 4096, 0, 0, 0, 0);
    softmax_kernel<<<4096, 256, 0, stream>>>(S);
    // o_t[i][c] = sum_j P[i][j] v[c][j]          (M=4096, N=512, K=4096)
    gemm_bt_kernel<true><<<dim3(32, 4, 1), 256, 0, stream>>>(S, v + b * sBN, o + b * sBN,
        nullptr, nullptr, nullptr, 1.f, 4096, 4096, 4096, 512, 0, 0, 0, 0);
  }

  // out[oc][n] = sum_c wp[oc][c] o_t[n][c] + bp[oc] + x   (M=512, N=4096)
  gemm_bt_kernel<false><<<dim3(4, 32, 2), 256, 0, stream>>>(wpb, o, out, bp, nullptr, x,
      1.f, 512, 512, 512, 4096, 0, sBN, sBN, sBN);
}

// Round 2
// 296.111 us; speedup vs baseline: 1.3714x; 1.3714x over previous
//
#include <hip/hip_runtime.h>
#include <hip/hip_bf16.h>

using bf16 = __hip_bfloat16;
typedef __attribute__((ext_vector_type(4))) float f32x4;
typedef __attribute__((ext_vector_type(8))) short bf16x8;

#define NPX 4096
#define CCH 512

struct Ptr4 { void* p0; void* p1; void* p2; void* p3; };

__device__ __forceinline__ void async16(const bf16* g, bf16* l) {
  __builtin_amdgcn_global_load_lds((const __attribute__((address_space(1))) void*)g,
                                   (__attribute__((address_space(3))) void*)l, 16, 0, 0);
}

__device__ __forceinline__ float bfb2f(short s) {
  unsigned u = ((unsigned)(unsigned short)s) << 16;
  float f;
  __builtin_memcpy(&f, &u, 4);
  return f;
}

__device__ __forceinline__ short f2bfb(float f) {
  bf16 h = __float2bfloat16(f);
  short s;
  __builtin_memcpy(&s, &h, 2);
  return s;
}

// ---------------- fused weight convert: [wq;wk;wv;wp] fp32 -> contiguous bf16,
// plus pack bqk = [bq;bk] ----------------
__global__ __launch_bounds__(256) void convert_weights_kernel(
    const float* __restrict__ wq, const float* __restrict__ wk,
    const float* __restrict__ wv, const float* __restrict__ wp,
    const float* __restrict__ bq, const float* __restrict__ bk,
    bf16* __restrict__ wout, float* __restrict__ bqk) {
  int tid = blockIdx.x * 256 + threadIdx.x;
  int i = tid * 4;  // i in [0, 1M)
  int seg = i >> 18;
  const float* in = seg == 0 ? wq : seg == 1 ? wk : seg == 2 ? wv : wp;
  float4 v = *reinterpret_cast<const float4*>(in + (i & 262143));
  wout[i]     = __float2bfloat16(v.x);
  wout[i + 1] = __float2bfloat16(v.y);
  wout[i + 2] = __float2bfloat16(v.z);
  wout[i + 3] = __float2bfloat16(v.w);
  if (tid < 256) {
    int j = tid * 4;
    const float* bsrc = j < 512 ? bq : bk;
    float4 b = *reinterpret_cast<const float4*>(bsrc + (j & 511));
    *reinterpret_cast<float4*>(bqk + j) = b;
  }
}

// ---------------- GroupNorm stats: one block per (b,g) ----------------
__global__ __launch_bounds__(256) void gn_stats_kernel(const float* __restrict__ x,
                                                       float* __restrict__ stats) {
  const float* p = x + (size_t)blockIdx.x * 65536;
  float s = 0.f, s2 = 0.f;
  int t = threadIdx.x;
  for (int i = t * 4; i < 65536; i += 256 * 4) {
    float4 v = *reinterpret_cast<const float4*>(p + i);
    s  += v.x + v.y + v.z + v.w;
    s2 += v.x * v.x + v.y * v.y + v.z * v.z + v.w * v.w;
  }
  #pragma unroll
  for (int off = 32; off >= 1; off >>= 1) {
    s  += __shfl_xor(s, off);
    s2 += __shfl_xor(s2, off);
  }
  __shared__ float ls[8];
  int wv = t >> 6;
  if ((t & 63) == 0) { ls[wv * 2] = s; ls[wv * 2 + 1] = s2; }
  __syncthreads();
  if (t == 0) {
    float S  = ls[0] + ls[2] + ls[4] + ls[6];
    float S2 = ls[1] + ls[3] + ls[5] + ls[7];
    float mean = S * (1.f / 65536.f);
    float var  = S2 * (1.f / 65536.f) - mean * mean;
    stats[blockIdx.x * 2]     = mean;
    stats[blockIdx.x * 2 + 1] = rsqrtf(var + 1e-6f);
  }
}

// ---------------- GroupNorm apply + transpose to [n][c] bf16 ----------------
__global__ __launch_bounds__(256) void gn_apply_kernel(const float* __restrict__ x,
    const float* __restrict__ stats, const float* __restrict__ gamma,
    const float* __restrict__ beta, bf16* __restrict__ h) {
  __shared__ float tile[64][65];
  int b  = blockIdx.z;
  int c0 = blockIdx.x * 64, n0 = blockIdx.y * 64;
  int t  = threadIdx.x;
  int cl = t >> 6, nl = t & 63;
  #pragma unroll
  for (int i = 0; i < 16; i++) {
    int c = c0 + cl + i * 4;
    float v = x[((size_t)b * CCH + c) * NPX + n0 + nl];
    int g = c >> 4;
    float mean = stats[(b * 32 + g) * 2];
    float rstd = stats[(b * 32 + g) * 2 + 1];
    tile[cl + i * 4][nl] = (v - mean) * rstd * gamma[c] + beta[c];
  }
  __syncthreads();
  #pragma unroll
  for (int i = 0; i < 16; i++) {
    int n = cl + i * 4;
    int c = nl;
    h[((size_t)b * NPX + n0 + n) * CCH + c0 + c] = __float2bfloat16(tile[c][n]);
  }
}

// ---------------- B^T GEMM: C[m][n] = alpha * sum_k A[m][k] B[n][k] (+biases/resid)
template<bool OUT_BF16>
__global__ __launch_bounds__(256, 2) void gemm_bt_kernel(
    const bf16* __restrict__ A, const bf16* __restrict__ B, void* __restrict__ C,
    const float* __restrict__ bias_m, const float* __restrict__ bias_n,
    const float* __restrict__ resid, float alpha, int K,
    int lda, int ldb, int ldc,
    long long sA, long long sB, long long sC, long long sR) {
  int bz = blockIdx.z;
  A += (size_t)bz * sA;
  B += (size_t)bz * sB;
  const int m0 = blockIdx.x * 128, n0 = blockIdx.y * 128;

  __shared__ bf16 ldsA[128 * 64];
  __shared__ bf16 ldsB[128 * 64];

  const int t = threadIdx.x;
  const int lane = t & 63, wv = t >> 6;
  const int wr = (wv >> 1) * 64, wc = (wv & 1) * 64;

  const int r0 = t >> 3;
  const int cb = ((t & 7) << 4) ^ ((r0 & 7) << 4);
  const bf16* gA = A + (size_t)(m0 + r0) * lda + (cb >> 1);
  const bf16* gB = B + (size_t)(n0 + r0) * ldb + (cb >> 1);
  bf16* lA = ldsA + t * 8;
  bf16* lB = ldsB + t * 8;

  const int arow = wr + (lane & 15);
  const int brow = wc + (lane & 15);
  const int kb   = (lane >> 4) * 16;

  f32x4 acc[4][4] = {};

  for (int k0 = 0; k0 < K; k0 += 64) {
    #pragma unroll
    for (int i = 0; i < 4; i++) {
      async16(gA + (size_t)i * 32 * lda + k0, lA + i * 2048);
      async16(gB + (size_t)i * 32 * ldb + k0, lB + i * 2048);
    }
    __syncthreads();
    #pragma unroll
    for (int ks = 0; ks < 2; ks++) {
      bf16x8 af[4], bfr[4];
      #pragma unroll
      for (int f = 0; f < 4; f++) {
        int ra = arow + f * 16;
        af[f] = *reinterpret_cast<const bf16x8*>(
            reinterpret_cast<const char*>(ldsA) + ra * 128 + ((ks * 64 + kb) ^ ((ra & 7) << 4)));
        int rb = brow + f * 16;
        bfr[f] = *reinterpret_cast<const bf16x8*>(
            reinterpret_cast<const char*>(ldsB) + rb * 128 + ((ks * 64 + kb) ^ ((rb & 7) << 4)));
      }
      #pragma unroll
      for (int fm = 0; fm < 4; fm++)
        #pragma unroll
        for (int fn = 0; fn < 4; fn++)
          acc[fm][fn] = __builtin_amdgcn_mfma_f32_16x16x32_bf16(af[fm], bfr[fn], acc[fm][fn], 0, 0, 0);
    }
    __syncthreads();
  }

  #pragma unroll
  for (int fm = 0; fm < 4; fm++) {
    #pragma unroll
    for (int j = 0; j < 4; j++) {
      int gm = m0 + wr + fm * 16 + (lane >> 4) * 4 + j;
      float bm = bias_m ? bias_m[gm] : 0.f;
      #pragma unroll
      for (int fn = 0; fn < 4; fn++) {
        int gn = n0 + wc + fn * 16 + (lane & 15);
        float vv = acc[fm][fn][j] * alpha + bm;
        if (bias_n) vv += bias_n[gn];
        if (resid)  vv += resid[(size_t)bz * sR + (size_t)gm * ldc + gn];
        if (OUT_BF16)
          reinterpret_cast<bf16*>(C)[(size_t)bz * sC + (size_t)gm * ldc + gn] = __float2bfloat16(vv);
        else
          reinterpret_cast<float*>(C)[(size_t)bz * sC + (size_t)gm * ldc + gn] = vv;
      }
    }
  }
}

// ---------------- PV with split-K=2: z -> (batch, k-split); partial -> slots[z] ---
__global__ __launch_bounds__(256, 2) void pv_split_kernel(
    const bf16* __restrict__ Sb, const bf16* __restrict__ vb,
    long long sS, long long sV, Ptr4 slots, int bFix) {
  const int z = blockIdx.z;
  const int b = (bFix >= 0) ? bFix : (z >> 1);
  const int s = (bFix >= 0) ? z : (z & 1);
  const bf16* A = Sb + (size_t)b * sS + s * 2048;
  const bf16* B = vb + (size_t)b * sV + s * 2048;
  bf16* Cp = (bf16*)((&slots.p0)[z]);
  const int m0 = blockIdx.x * 128, n0 = blockIdx.y * 128;

  __shared__ bf16 ldsA[128 * 64];
  __shared__ bf16 ldsB[128 * 64];

  const int t = threadIdx.x;
  const int lane = t & 63, wv = t >> 6;
  const int wr = (wv >> 1) * 64, wc = (wv & 1) * 64;

  const int r0 = t >> 3;
  const int cb = ((t & 7) << 4) ^ ((r0 & 7) << 4);
  const bf16* gA = A + (size_t)(m0 + r0) * 4096 + (cb >> 1);
  const bf16* gB = B + (size_t)(n0 + r0) * 4096 + (cb >> 1);
  bf16* lA = ldsA + t * 8;
  bf16* lB = ldsB + t * 8;

  const int arow = wr + (lane & 15);
  const int brow = wc + (lane & 15);
  const int kb   = (lane >> 4) * 16;

  f32x4 acc[4][4] = {};

  for (int k0 = 0; k0 < 2048; k0 += 64) {
    #pragma unroll
    for (int i = 0; i < 4; i++) {
      async16(gA + (size_t)i * 32 * 4096 + k0, lA + i * 2048);
      async16(gB + (size_t)i * 32 * 4096 + k0, lB + i * 2048);
    }
    __syncthreads();
    #pragma unroll
    for (int ks = 0; ks < 2; ks++) {
      bf16x8 af[4], bfr[4];
      #pragma unroll
      for (int f = 0; f < 4; f++) {
        int ra = arow + f * 16;
        af[f] = *reinterpret_cast<const bf16x8*>(
            reinterpret_cast<const char*>(ldsA) + ra * 128 + ((ks * 64 + kb) ^ ((ra & 7) << 4)));
        int rb = brow + f * 16;
        bfr[f] = *reinterpret_cast<const bf16x8*>(
            reinterpret_cast<const char*>(ldsB) + rb * 128 + ((ks * 64 + kb) ^ ((rb & 7) << 4)));
      }
      #pragma unroll
      for (int fm = 0; fm < 4; fm++)
        #pragma unroll
        for (int fn = 0; fn < 4; fn++)
          acc[fm][fn] = __builtin_amdgcn_mfma_f32_16x16x32_bf16(af[fm], bfr[fn], acc[fm][fn], 0, 0, 0);
    }
    __syncthreads();
  }

  #pragma unroll
  for (int fm = 0; fm < 4; fm++) {
    #pragma unroll
    for (int j = 0; j < 4; j++) {
      int gm = m0 + wr + fm * 16 + (lane >> 4) * 4 + j;
      #pragma unroll
      for (int fn = 0; fn < 4; fn++) {
        int gn = n0 + wc + fn * 16 + (lane & 15);
        Cp[(size_t)gm * 512 + gn] = __float2bfloat16(acc[fm][fn][j]);
      }
    }
  }
}

// ---------------- dst[i] += src[i] (bf16) ----------------
__global__ __launch_bounds__(256) void reduce_add_kernel(bf16* __restrict__ dst,
                                                         const bf16* __restrict__ src, int n) {
  int i = (blockIdx.x * 256 + threadIdx.x) * 8;
  if (i + 7 < n) {
    bf16x8 a = *reinterpret_cast<const bf16x8*>(dst + i);
    bf16x8 b = *reinterpret_cast<const bf16x8*>(src + i);
    bf16x8 r;
    #pragma unroll
    for (int j = 0; j < 8; j++) r[j] = f2bfb(bfb2f(a[j]) + bfb2f(b[j]));
    *reinterpret_cast<bf16x8*>(dst + i) = r;
  }
}

// ---------------- row softmax, in place on bf16 [4096] rows ----------------
__global__ __launch_bounds__(256) void softmax_kernel(bf16* __restrict__ S) {
  bf16* p = S + (size_t)blockIdx.x * NPX;
  int t = threadIdx.x;
  bf16x8 r0 = *reinterpret_cast<const bf16x8*>(p + t * 8);
  bf16x8 r1 = *reinterpret_cast<const bf16x8*>(p + 2048 + t * 8);
  float v[16];
  #pragma unroll
  for (int i = 0; i < 8; i++) {
    v[i]     = bfb2f(r0[i]);
    v[i + 8] = bfb2f(r1[i]);
  }
  float mx = -3e38f;
  #pragma unroll
  for (int i = 0; i < 16; i++) mx = fmaxf(mx, v[i]);
  #pragma unroll
  for (int off = 32; off >= 1; off >>= 1) mx = fmaxf(mx, __shfl_xor(mx, off));
  __shared__ float lsm[4];
  if ((t & 63) == 0) lsm[t >> 6] = mx;
  __syncthreads();
  mx = fmaxf(fmaxf(lsm[0], lsm[1]), fmaxf(lsm[2], lsm[3]));
  float sum = 0.f;
  #pragma unroll
  for (int i = 0; i < 16; i++) {
    v[i] = __expf(v[i] - mx);
    sum += v[i];
  }
  #pragma unroll
  for (int off = 32; off >= 1; off >>= 1) sum += __shfl_xor(sum, off);
  __shared__ float lss[4];
  if ((t & 63) == 0) lss[t >> 6] = sum;
  __syncthreads();
  sum = lss[0] + lss[1] + lss[2] + lss[3];
  float inv = 1.f / sum;
  bf16x8 o0, o1;
  #pragma unroll
  for (int i = 0; i < 8; i++) {
    o0[i] = f2bfb(v[i] * inv);
    o1[i] = f2bfb(v[i + 8] * inv);
  }
  *reinterpret_cast<bf16x8*>(p + t * 8) = o0;
  *reinterpret_cast<bf16x8*>(p + 2048 + t * 8) = o1;
}

extern "C" void kernel_launch(void* const* d_in, const int* in_sizes, int n_in,
                              void* d_out, int out_size, void* d_ws, size_t ws_size,
                              hipStream_t stream) {
  const float* x     = (const float*)d_in[0];
  const float* gamma = (const float*)d_in[1];
  const float* beta  = (const float*)d_in[2];
  const float* wq    = (const float*)d_in[3];
  const float* bq    = (const float*)d_in[4];
  const float* wk    = (const float*)d_in[5];
  const float* bk    = (const float*)d_in[6];
  const float* wv    = (const float*)d_in[7];
  const float* bv    = (const float*)d_in[8];
  const float* wp    = (const float*)d_in[9];
  const float* bp    = (const float*)d_in[10];
  float* out = (float*)d_out;

  char* w = (char*)d_ws;
  size_t off = 0;
  float* stats = (float*)(w + off);    off += 4096;
  float* bqk   = (float*)(w + off);    off += 4096;
  bf16* wqkb = (bf16*)(w + off);       off += (size_t)1024 * 512 * 2;  // [wq;wk], then wv, wp follow
  bf16* wvb  = (bf16*)(w + off);       off += (size_t)512 * 512 * 2;
  bf16* wpb  = (bf16*)(w + off);       off += (size_t)512 * 512 * 2;
  bf16* h    = (bf16*)(w + off);       off += (size_t)2 * NPX * CCH * 2;
  bf16* qk   = (bf16*)(w + off);       off += (size_t)2 * NPX * 1024 * 2;
  bf16* v    = (bf16*)(w + off);       off += (size_t)2 * NPX * CCH * 2;
  bf16* o    = (bf16*)(w + off);       off += (size_t)2 * NPX * CCH * 2;
  bf16* S    = (bf16*)(w + off);
  size_t need_big = off + (size_t)2 * NPX * NPX * 2;   // 2-batch S
  size_t need_sml = off + (size_t)NPX * NPX * 2;       // 1-batch S
  const bool big = ws_size >= need_big;
  (void)need_sml;

  const long long sBN = (long long)NPX * CCH;      // 4096*512
  const long long sQK = (long long)NPX * 1024;     // 4096*1024
  const long long sS  = (long long)NPX * NPX;      // 4096*4096
  const float scale = 0.04419417382415922f;        // 512^-0.5

  convert_weights_kernel<<<1024, 256, 0, stream>>>(wq, wk, wv, wp, bq, bk, wqkb, bqk);
  gn_stats_kernel<<<64, 256, 0, stream>>>(x, stats);
  gn_apply_kernel<<<dim3(8, 64, 2), 256, 0, stream>>>(x, stats, gamma, beta, h);

  // qk[n][0..1024) = h[n][:] @ [wq;wk]^T + [bq;bk]   (M=4096, N=1024, K=512)
  gemm_bt_kernel<true><<<dim3(32, 8, 2), 256, 0, stream>>>(h, wqkb, qk, nullptr, bqk, nullptr,
      1.f, 512, 512, 512, 1024, sBN, 0, sQK, 0);
  // v[c][n] = wv[c][:] @ h[n][:] + bv[c]             (M=512, N=4096, K=512)
  gemm_bt_kernel<true><<<dim3(4, 32, 2), 256, 0, stream>>>(wvb, h, v, bv, nullptr, nullptr,
      1.f, 512, 512, 512, 4096, 0, sBN, sBN, 0);

  if (big) {
    // S[b][i][j] = scale * q_i . k_j   (both batches, one launch)
    gemm_bt_kernel<true><<<dim3(32, 32, 2), 256, 0, stream>>>(qk, qk + 512, S,
        nullptr, nullptr, nullptr, scale, 512, 1024, 1024, 4096, sQK, sQK, sS, 0);
    softmax_kernel<<<8192, 256, 0, stream>>>(S);
    // PV split-K=2, both batches: partials -> {h, o_b0, qk_lo, o_b1}
    Ptr4 slots{h, o, qk, o + sBN};
    pv_split_kernel<<<dim3(32, 4, 4), 256, 0, stream>>>(S, v, sS, sBN, slots, -1);
    reduce_add_kernel<<<1024, 256, 0, stream>>>(o, h, NPX * CCH);
    reduce_add_kernel<<<1024, 256, 0, stream>>>(o + sBN, qk, NPX * CCH);
  } else {
    for (int b = 0; b < 2; b++) {
      gemm_bt_kernel<true><<<dim3(32, 32, 1), 256, 0, stream>>>(qk + b * sQK, qk + b * sQK + 512, S,
          nullptr, nullptr, nullptr, scale, 512, 1024, 1024, 4096, 0, 0, 0, 0);
      softmax_kernel<<<4096, 256, 0, stream>>>(S);
      Ptr4 slots{h, o + b * sBN, h, h};
      pv_split_kernel<<<dim3(32, 4, 2), 256, 0, stream>>>(S, v, 0, sBN * 0 + (long long)b * sBN, slots, b);
      // note: b passed via bFix; batch offset applied through sV arg below
      reduce_add_kernel<<<1024, 256, 0, stream>>>(o + b * sBN, h, NPX * CCH);
    }
  }

  // out[c][n] = wp[c][:] @ o[n][:] + bp[c] + x       (M=512, N=4096, K=512)
  gemm_bt_kernel<false><<<dim3(4, 32, 2), 256, 0, stream>>>(wpb, o, out, bp, nullptr, x,
      1.f, 512, 512, 512, 4096, 0, sBN, sBN, sBN);
}

// Round 4
// 286.732 us; speedup vs baseline: 1.4163x; 1.0327x over previous
//
#include <hip/hip_runtime.h>
#include <hip/hip_bf16.h>

using bf16 = __hip_bfloat16;
typedef __attribute__((ext_vector_type(4))) float f32x4;
typedef __attribute__((ext_vector_type(8))) short bf16x8;

#define NPX 4096
#define CCH 512

struct Ptr4 { void* p0; void* p1; void* p2; void* p3; };

__device__ __forceinline__ void async16(const bf16* g, bf16* l) {
  __builtin_amdgcn_global_load_lds((const __attribute__((address_space(1))) void*)g,
                                   (__attribute__((address_space(3))) void*)l, 16, 0, 0);
}

__device__ __forceinline__ float bfb2f(short s) {
  unsigned u = ((unsigned)(unsigned short)s) << 16;
  float f;
  __builtin_memcpy(&f, &u, 4);
  return f;
}

__device__ __forceinline__ short f2bfb(float f) {
  bf16 h = __float2bfloat16(f);
  short s;
  __builtin_memcpy(&s, &h, 2);
  return s;
}

// XCD-aware bijective swizzle of flat block id (nwg % 8 == 0 for all our grids).
__device__ __forceinline__ void xcd_swz(unsigned& bx, unsigned& by, unsigned& bz) {
  unsigned nx = gridDim.x, ny = gridDim.y;
  unsigned flat = (blockIdx.z * ny + blockIdx.y) * nx + blockIdx.x;
  unsigned nwg = nx * ny * gridDim.z;
  unsigned swz = (flat & 7) * (nwg >> 3) + (flat >> 3);
  bx = swz % nx;
  unsigned tmp = swz / nx;
  by = tmp % ny;
  bz = tmp / ny;
}

// ---------------- fused weight convert + bias pack + rowsum zero ----------------
__global__ __launch_bounds__(256) void convert_weights_kernel(
    const float* __restrict__ wq, const float* __restrict__ wk,
    const float* __restrict__ wv, const float* __restrict__ wp,
    const float* __restrict__ bq, const float* __restrict__ bk,
    bf16* __restrict__ wout, float* __restrict__ bqk, float* __restrict__ rowsum) {
  int tid = blockIdx.x * 256 + threadIdx.x;
  int i = tid * 4;  // i in [0, 1M)
  int seg = i >> 18;
  const float* in = seg == 0 ? wq : seg == 1 ? wk : seg == 2 ? wv : wp;
  float4 v = *reinterpret_cast<const float4*>(in + (i & 262143));
  wout[i]     = __float2bfloat16(v.x);
  wout[i + 1] = __float2bfloat16(v.y);
  wout[i + 2] = __float2bfloat16(v.z);
  wout[i + 3] = __float2bfloat16(v.w);
  if (tid < 256) {
    int j = tid * 4;
    const float* bsrc = j < 512 ? bq : bk;
    float4 b = *reinterpret_cast<const float4*>(bsrc + (j & 511));
    *reinterpret_cast<float4*>(bqk + j) = b;
  }
  if (tid < 2048) {
    float4 z = {0.f, 0.f, 0.f, 0.f};
    *reinterpret_cast<float4*>(rowsum + tid * 4) = z;
  }
}

// ---------------- GroupNorm stats: one block per (b,g) ----------------
__global__ __launch_bounds__(256) void gn_stats_kernel(const float* __restrict__ x,
                                                       float* __restrict__ stats) {
  const float* p = x + (size_t)blockIdx.x * 65536;
  float s = 0.f, s2 = 0.f;
  int t = threadIdx.x;
  for (int i = t * 4; i < 65536; i += 256 * 4) {
    float4 v = *reinterpret_cast<const float4*>(p + i);
    s  += v.x + v.y + v.z + v.w;
    s2 += v.x * v.x + v.y * v.y + v.z * v.z + v.w * v.w;
  }
  #pragma unroll
  for (int off = 32; off >= 1; off >>= 1) {
    s  += __shfl_xor(s, off);
    s2 += __shfl_xor(s2, off);
  }
  __shared__ float ls[8];
  int wv = t >> 6;
  if ((t & 63) == 0) { ls[wv * 2] = s; ls[wv * 2 + 1] = s2; }
  __syncthreads();
  if (t == 0) {
    float S  = ls[0] + ls[2] + ls[4] + ls[6];
    float S2 = ls[1] + ls[3] + ls[5] + ls[7];
    float mean = S * (1.f / 65536.f);
    float var  = S2 * (1.f / 65536.f) - mean * mean;
    stats[blockIdx.x * 2]     = mean;
    stats[blockIdx.x * 2 + 1] = rsqrtf(var + 1e-6f);
  }
}

// ---------------- GroupNorm apply + transpose to [n][c] bf16 ----------------
__global__ __launch_bounds__(256) void gn_apply_kernel(const float* __restrict__ x,
    const float* __restrict__ stats, const float* __restrict__ gamma,
    const float* __restrict__ beta, bf16* __restrict__ h) {
  __shared__ float tile[64][65];
  int b  = blockIdx.z;
  int c0 = blockIdx.x * 64, n0 = blockIdx.y * 64;
  int t  = threadIdx.x;
  int cl = t >> 6, nl = t & 63;
  #pragma unroll
  for (int i = 0; i < 16; i++) {
    int c = c0 + cl + i * 4;
    float v = x[((size_t)b * CCH + c) * NPX + n0 + nl];
    int g = c >> 4;
    float mean = stats[(b * 32 + g) * 2];
    float rstd = stats[(b * 32 + g) * 2 + 1];
    tile[cl + i * 4][nl] = (v - mean) * rstd * gamma[c] + beta[c];
  }
  __syncthreads();
  #pragma unroll
  for (int i = 0; i < 16; i++) {
    int n = cl + i * 4;
    int c = nl;
    h[((size_t)b * NPX + n0 + n) * CCH + c0 + c] = __float2bfloat16(tile[c][n]);
  }
}

// ---------------- B^T GEMM: C[m][n] = f(alpha * sum_k A[m][k] B[n][k])
// OMODE: 0 = f32 out (+bias/resid), 1 = bf16 out (+bias), 2 = bf16 exp-out + rowsum
template<int OMODE>
__global__ __launch_bounds__(256, 2) void gemm_bt_kernel(
    const bf16* __restrict__ A, const bf16* __restrict__ B, void* __restrict__ C,
    const float* __restrict__ bias_m, const float* __restrict__ bias_n,
    const float* __restrict__ resid, float* __restrict__ rowsum, float alpha, int K,
    int lda, int ldb, int ldc,
    long long sA, long long sB, long long sC, long long sR) {
  unsigned bxi, byi, bz;
  xcd_swz(bxi, byi, bz);
  A += (size_t)bz * sA;
  B += (size_t)bz * sB;
  const int m0 = bxi * 128, n0 = byi * 128;

  __shared__ bf16 ldsA[128 * 64];
  __shared__ bf16 ldsB[128 * 64];

  const int t = threadIdx.x;
  const int lane = t & 63, wv = t >> 6;
  const int wr = (wv >> 1) * 64, wc = (wv & 1) * 64;

  const int r0 = t >> 3;
  const int cb = ((t & 7) << 4) ^ ((r0 & 7) << 4);
  const bf16* gA = A + (size_t)(m0 + r0) * lda + (cb >> 1);
  const bf16* gB = B + (size_t)(n0 + r0) * ldb + (cb >> 1);
  bf16* lA = ldsA + t * 8;
  bf16* lB = ldsB + t * 8;

  const int arow = wr + (lane & 15);
  const int brow = wc + (lane & 15);
  const int kb   = (lane >> 4) * 16;

  f32x4 acc[4][4] = {};

  for (int k0 = 0; k0 < K; k0 += 64) {
    #pragma unroll
    for (int i = 0; i < 4; i++) {
      async16(gA + (size_t)i * 32 * lda + k0, lA + i * 2048);
      async16(gB + (size_t)i * 32 * ldb + k0, lB + i * 2048);
    }
    __syncthreads();
    #pragma unroll
    for (int ks = 0; ks < 2; ks++) {
      bf16x8 af[4], bfr[4];
      #pragma unroll
      for (int f = 0; f < 4; f++) {
        int ra = arow + f * 16;
        af[f] = *reinterpret_cast<const bf16x8*>(
            reinterpret_cast<const char*>(ldsA) + ra * 128 + ((ks * 64 + kb) ^ ((ra & 7) << 4)));
        int rb = brow + f * 16;
        bfr[f] = *reinterpret_cast<const bf16x8*>(
            reinterpret_cast<const char*>(ldsB) + rb * 128 + ((ks * 64 + kb) ^ ((rb & 7) << 4)));
      }
      #pragma unroll
      for (int fm = 0; fm < 4; fm++)
        #pragma unroll
        for (int fn = 0; fn < 4; fn++)
          acc[fm][fn] = __builtin_amdgcn_mfma_f32_16x16x32_bf16(af[fm], bfr[fn], acc[fm][fn], 0, 0, 0);
    }
    __syncthreads();
  }

  #pragma unroll
  for (int fm = 0; fm < 4; fm++) {
    #pragma unroll
    for (int j = 0; j < 4; j++) {
      int gm = m0 + wr + fm * 16 + (lane >> 4) * 4 + j;
      if (OMODE == 2) {
        float rsum = 0.f;
        #pragma unroll
        for (int fn = 0; fn < 4; fn++) {
          int gn = n0 + wc + fn * 16 + (lane & 15);
          float e = __expf(acc[fm][fn][j] * alpha);
          rsum += e;
          reinterpret_cast<bf16*>(C)[(size_t)bz * sC + (size_t)gm * ldc + gn] = __float2bfloat16(e);
        }
        rsum += __shfl_xor(rsum, 1);
        rsum += __shfl_xor(rsum, 2);
        rsum += __shfl_xor(rsum, 4);
        rsum += __shfl_xor(rsum, 8);
        if ((lane & 15) == 0) atomicAdd(rowsum + bz * 4096 + gm, rsum);
      } else {
        float bm = bias_m ? bias_m[gm] : 0.f;
        #pragma unroll
        for (int fn = 0; fn < 4; fn++) {
          int gn = n0 + wc + fn * 16 + (lane & 15);
          float vv = acc[fm][fn][j] * alpha + bm;
          if (bias_n) vv += bias_n[gn];
          if (resid)  vv += resid[(size_t)bz * sR + (size_t)gm * ldc + gn];
          if (OMODE == 1)
            reinterpret_cast<bf16*>(C)[(size_t)bz * sC + (size_t)gm * ldc + gn] = __float2bfloat16(vv);
          else
            reinterpret_cast<float*>(C)[(size_t)bz * sC + (size_t)gm * ldc + gn] = vv;
        }
      }
    }
  }
}

// ---------------- PV with split-K=2, normalized by 1/rowsum --------------------
// split_only=0: z -> (b = z>>1, s = z&1). split_only=1: b=0 (pointers pre-offset), s=z.
__global__ __launch_bounds__(256, 2) void pv_split_kernel(
    const bf16* __restrict__ Sb, const bf16* __restrict__ vb,
    const float* __restrict__ rowsum,
    long long sS, long long sV, Ptr4 slots, int split_only) {
  unsigned bxi, byi, bz;
  xcd_swz(bxi, byi, bz);
  const int z = bz;
  const int b = split_only ? 0 : (z >> 1);
  const int s = split_only ? z : (z & 1);
  const bf16* A = Sb + (size_t)b * sS + s * 2048;
  const bf16* B = vb + (size_t)b * sV + s * 2048;
  const float* rs = rowsum + b * 4096;
  bf16* Cp = (bf16*)((&slots.p0)[z]);
  const int m0 = bxi * 128, n0 = byi * 128;

  __shared__ bf16 ldsA[128 * 64];
  __shared__ bf16 ldsB[128 * 64];

  const int t = threadIdx.x;
  const int lane = t & 63, wv = t >> 6;
  const int wr = (wv >> 1) * 64, wc = (wv & 1) * 64;

  const int r0 = t >> 3;
  const int cb = ((t & 7) << 4) ^ ((r0 & 7) << 4);
  const bf16* gA = A + (size_t)(m0 + r0) * 4096 + (cb >> 1);
  const bf16* gB = B + (size_t)(n0 + r0) * 4096 + (cb >> 1);
  bf16* lA = ldsA + t * 8;
  bf16* lB = ldsB + t * 8;

  const int arow = wr + (lane & 15);
  const int brow = wc + (lane & 15);
  const int kb   = (lane >> 4) * 16;

  f32x4 acc[4][4] = {};

  for (int k0 = 0; k0 < 2048; k0 += 64) {
    #pragma unroll
    for (int i = 0; i < 4; i++) {
      async16(gA + (size_t)i * 32 * 4096 + k0, lA + i * 2048);
      async16(gB + (size_t)i * 32 * 4096 + k0, lB + i * 2048);
    }
    __syncthreads();
    #pragma unroll
    for (int ks = 0; ks < 2; ks++) {
      bf16x8 af[4], bfr[4];
      #pragma unroll
      for (int f = 0; f < 4; f++) {
        int ra = arow + f * 16;
        af[f] = *reinterpret_cast<const bf16x8*>(
            reinterpret_cast<const char*>(ldsA) + ra * 128 + ((ks * 64 + kb) ^ ((ra & 7) << 4)));
        int rb = brow + f * 16;
        bfr[f] = *reinterpret_cast<const bf16x8*>(
            reinterpret_cast<const char*>(ldsB) + rb * 128 + ((ks * 64 + kb) ^ ((rb & 7) << 4)));
      }
      #pragma unroll
      for (int fm = 0; fm < 4; fm++)
        #pragma unroll
        for (int fn = 0; fn < 4; fn++)
          acc[fm][fn] = __builtin_amdgcn_mfma_f32_16x16x32_bf16(af[fm], bfr[fn], acc[fm][fn], 0, 0, 0);
    }
    __syncthreads();
  }

  #pragma unroll
  for (int fm = 0; fm < 4; fm++) {
    #pragma unroll
    for (int j = 0; j < 4; j++) {
      int gm = m0 + wr + fm * 16 + (lane >> 4) * 4 + j;
      float inv = 1.0f / rs[gm];
      #pragma unroll
      for (int fn = 0; fn < 4; fn++) {
        int gn = n0 + wc + fn * 16 + (lane & 15);
        Cp[(size_t)gm * 512 + gn] = __float2bfloat16(acc[fm][fn][j] * inv);
      }
    }
  }
}

// ---------------- dst[i] += src[i] (bf16) ----------------
__global__ __launch_bounds__(256) void reduce_add_kernel(bf16* __restrict__ dst,
                                                         const bf16* __restrict__ src, int n) {
  int i = (blockIdx.x * 256 + threadIdx.x) * 8;
  if (i + 7 < n) {
    bf16x8 a = *reinterpret_cast<const bf16x8*>(dst + i);
    bf16x8 b = *reinterpret_cast<const bf16x8*>(src + i);
    bf16x8 r;
    #pragma unroll
    for (int j = 0; j < 8; j++) r[j] = f2bfb(bfb2f(a[j]) + bfb2f(b[j]));
    *reinterpret_cast<bf16x8*>(dst + i) = r;
  }
}

extern "C" void kernel_launch(void* const* d_in, const int* in_sizes, int n_in,
                              void* d_out, int out_size, void* d_ws, size_t ws_size,
                              hipStream_t stream) {
  const float* x     = (const float*)d_in[0];
  const float* gamma = (const float*)d_in[1];
  const float* beta  = (const float*)d_in[2];
  const float* wq    = (const float*)d_in[3];
  const float* bq    = (const float*)d_in[4];
  const float* wk    = (const float*)d_in[5];
  const float* bk    = (const float*)d_in[6];
  const float* wv    = (const float*)d_in[7];
  const float* bv    = (const float*)d_in[8];
  const float* wp    = (const float*)d_in[9];
  const float* bp    = (const float*)d_in[10];
  float* out = (float*)d_out;

  char* w = (char*)d_ws;
  size_t off = 0;
  float* stats  = (float*)(w + off);   off += 4096;
  float* bqk    = (float*)(w + off);   off += 4096;
  float* rowsum = (float*)(w + off);   off += 32768;  // [2][4096] f32
  bf16* wqkb = (bf16*)(w + off);       off += (size_t)1024 * 512 * 2;  // [wq;wk] then wv, wp
  bf16* wvb  = (bf16*)(w + off);       off += (size_t)512 * 512 * 2;
  bf16* wpb  = (bf16*)(w + off);       off += (size_t)512 * 512 * 2;
  bf16* h    = (bf16*)(w + off);       off += (size_t)2 * NPX * CCH * 2;
  bf16* qk   = (bf16*)(w + off);       off += (size_t)2 * NPX * 1024 * 2;
  bf16* v    = (bf16*)(w + off);       off += (size_t)2 * NPX * CCH * 2;
  bf16* o    = (bf16*)(w + off);       off += (size_t)2 * NPX * CCH * 2;
  bf16* S    = (bf16*)(w + off);
  size_t need_big = off + (size_t)2 * NPX * NPX * 2;
  const bool big = ws_size >= need_big;

  const long long sBN = (long long)NPX * CCH;      // 4096*512
  const long long sQK = (long long)NPX * 1024;     // 4096*1024
  const long long sS  = (long long)NPX * NPX;      // 4096*4096
  const float scale = 0.04419417382415922f;        // 512^-0.5

  convert_weights_kernel<<<1024, 256, 0, stream>>>(wq, wk, wv, wp, bq, bk, wqkb, bqk, rowsum);
  gn_stats_kernel<<<64, 256, 0, stream>>>(x, stats);
  gn_apply_kernel<<<dim3(8, 64, 2), 256, 0, stream>>>(x, stats, gamma, beta, h);

  // qk[n][0..1024) = h[n][:] @ [wq;wk]^T + [bq;bk]   (M=4096, N=1024, K=512)
  gemm_bt_kernel<1><<<dim3(32, 8, 2), 256, 0, stream>>>(h, wqkb, qk, nullptr, bqk, nullptr,
      nullptr, 1.f, 512, 512, 512, 1024, sBN, 0, sQK, 0);
  // v[c][n] = wv[c][:] @ h[n][:] + bv[c]             (M=512, N=4096, K=512)
  gemm_bt_kernel<1><<<dim3(4, 32, 2), 256, 0, stream>>>(wvb, h, v, bv, nullptr, nullptr,
      nullptr, 1.f, 512, 512, 512, 4096, 0, sBN, sBN, 0);

  if (big) {
    // P[b][i][j] = exp(scale * q_i . k_j), rowsum accumulated (both batches)
    gemm_bt_kernel<2><<<dim3(32, 32, 2), 256, 0, stream>>>(qk, qk + 512, S,
        nullptr, nullptr, nullptr, rowsum, scale, 512, 1024, 1024, 4096, sQK, sQK, sS, 0);
    // PV split-K=2, normalized partials -> {h, o_b0, qk_lo, o_b1}
    Ptr4 slots{h, o, qk, o + sBN};
    pv_split_kernel<<<dim3(32, 4, 4), 256, 0, stream>>>(S, v, rowsum, sS, sBN, slots, 0);
    reduce_add_kernel<<<1024, 256, 0, stream>>>(o, h, NPX * CCH);
    reduce_add_kernel<<<1024, 256, 0, stream>>>(o + sBN, qk, NPX * CCH);
  } else {
    for (int b = 0; b < 2; b++) {
      gemm_bt_kernel<2><<<dim3(32, 32, 1), 256, 0, stream>>>(qk + b * sQK, qk + b * sQK + 512, S,
          nullptr, nullptr, nullptr, rowsum + b * 4096, scale, 512, 1024, 1024, 4096, 0, 0, 0, 0);
      Ptr4 slots{h, o + b * sBN, h, h};
      pv_split_kernel<<<dim3(32, 4, 2), 256, 0, stream>>>(S, v + b * sBN, rowsum + b * 4096,
          0, 0, slots, 1);
      reduce_add_kernel<<<1024, 256, 0, stream>>>(o + b * sBN, h, NPX * CCH);
    }
  }

  // out[c][n] = wp[c][:] @ o[n][:] + bp[c] + x       (M=512, N=4096, K=512)
  gemm_bt_kernel<0><<<dim3(4, 32, 2), 256, 0, stream>>>(wpb, o, out, bp, nullptr, x,
      nullptr, 1.f, 512, 512, 512, 4096, 0, sBN, sBN, sBN);
}

// Round 5
// 286.501 us; speedup vs baseline: 1.4174x; 1.0008x over previous
//
#include <hip/hip_runtime.h>
#include <hip/hip_bf16.h>

using bf16 = __hip_bfloat16;
typedef __attribute__((ext_vector_type(4))) float f32x4;
typedef __attribute__((ext_vector_type(8))) short bf16x8;

#define NPX 4096
#define CCH 512

struct Ptr4 { void* p0; void* p1; void* p2; void* p3; };

__device__ __forceinline__ void async16(const bf16* g, bf16* l) {
  __builtin_amdgcn_global_load_lds((const __attribute__((address_space(1))) void*)g,
                                   (__attribute__((address_space(3))) void*)l, 16, 0, 0);
}

__device__ __forceinline__ float bfb2f(short s) {
  unsigned u = ((unsigned)(unsigned short)s) << 16;
  float f;
  __builtin_memcpy(&f, &u, 4);
  return f;
}

__device__ __forceinline__ short f2bfb(float f) {
  bf16 h = __float2bfloat16(f);
  short s;
  __builtin_memcpy(&s, &h, 2);
  return s;
}

// XCD-aware bijective swizzle of flat block id (nwg % 8 == 0 for all our grids).
__device__ __forceinline__ void xcd_swz(unsigned& bx, unsigned& by, unsigned& bz) {
  unsigned nx = gridDim.x, ny = gridDim.y;
  unsigned flat = (blockIdx.z * ny + blockIdx.y) * nx + blockIdx.x;
  unsigned nwg = nx * ny * gridDim.z;
  unsigned swz = (flat & 7) * (nwg >> 3) + (flat >> 3);
  bx = swz % nx;
  unsigned tmp = swz / nx;
  by = tmp % ny;
  bz = tmp / ny;
}

// ---------------- fused weight convert + bias pack ----------------
__global__ __launch_bounds__(256) void convert_weights_kernel(
    const float* __restrict__ wq, const float* __restrict__ wk,
    const float* __restrict__ wv, const float* __restrict__ wp,
    const float* __restrict__ bq, const float* __restrict__ bk,
    bf16* __restrict__ wout, float* __restrict__ bqk) {
  int tid = blockIdx.x * 256 + threadIdx.x;
  int i = tid * 4;  // i in [0, 1M)
  int seg = i >> 18;
  const float* in = seg == 0 ? wq : seg == 1 ? wk : seg == 2 ? wv : wp;
  float4 v = *reinterpret_cast<const float4*>(in + (i & 262143));
  wout[i]     = __float2bfloat16(v.x);
  wout[i + 1] = __float2bfloat16(v.y);
  wout[i + 2] = __float2bfloat16(v.z);
  wout[i + 3] = __float2bfloat16(v.w);
  if (tid < 256) {
    int j = tid * 4;
    const float* bsrc = j < 512 ? bq : bk;
    float4 b = *reinterpret_cast<const float4*>(bsrc + (j & 511));
    *reinterpret_cast<float4*>(bqk + j) = b;
  }
}

// ---------------- GroupNorm stats: one block per (b,g) ----------------
__global__ __launch_bounds__(256) void gn_stats_kernel(const float* __restrict__ x,
                                                       float* __restrict__ stats) {
  const float* p = x + (size_t)blockIdx.x * 65536;
  float s = 0.f, s2 = 0.f;
  int t = threadIdx.x;
  for (int i = t * 4; i < 65536; i += 256 * 4) {
    float4 v = *reinterpret_cast<const float4*>(p + i);
    s  += v.x + v.y + v.z + v.w;
    s2 += v.x * v.x + v.y * v.y + v.z * v.z + v.w * v.w;
  }
  #pragma unroll
  for (int off = 32; off >= 1; off >>= 1) {
    s  += __shfl_xor(s, off);
    s2 += __shfl_xor(s2, off);
  }
  __shared__ float ls[8];
  int wv = t >> 6;
  if ((t & 63) == 0) { ls[wv * 2] = s; ls[wv * 2 + 1] = s2; }
  __syncthreads();
  if (t == 0) {
    float S  = ls[0] + ls[2] + ls[4] + ls[6];
    float S2 = ls[1] + ls[3] + ls[5] + ls[7];
    float mean = S * (1.f / 65536.f);
    float var  = S2 * (1.f / 65536.f) - mean * mean;
    stats[blockIdx.x * 2]     = mean;
    stats[blockIdx.x * 2 + 1] = rsqrtf(var + 1e-6f);
  }
}

// ---------------- GroupNorm apply + transpose to [n][c] bf16 ----------------
__global__ __launch_bounds__(256) void gn_apply_kernel(const float* __restrict__ x,
    const float* __restrict__ stats, const float* __restrict__ gamma,
    const float* __restrict__ beta, bf16* __restrict__ h) {
  __shared__ float tile[64][65];
  int b  = blockIdx.z;
  int c0 = blockIdx.x * 64, n0 = blockIdx.y * 64;
  int t  = threadIdx.x;
  int cl = t >> 6, nl = t & 63;
  #pragma unroll
  for (int i = 0; i < 16; i++) {
    int c = c0 + cl + i * 4;
    float v = x[((size_t)b * CCH + c) * NPX + n0 + nl];
    int g = c >> 4;
    float mean = stats[(b * 32 + g) * 2];
    float rstd = stats[(b * 32 + g) * 2 + 1];
    tile[cl + i * 4][nl] = (v - mean) * rstd * gamma[c] + beta[c];
  }
  __syncthreads();
  #pragma unroll
  for (int i = 0; i < 16; i++) {
    int n = cl + i * 4;
    int c = nl;
    h[((size_t)b * NPX + n0 + n) * CCH + c0 + c] = __float2bfloat16(tile[c][n]);
  }
}

// ---------------- B^T GEMM: C[m][n] = f(alpha * sum_k A[m][k] B[n][k])
// OMODE: 0 = f32 out (+bias/resid), 1 = bf16 out (+bias),
//        2 = bf16 exp-out + per-(block,wavecol) partial rowsum stores (no atomics)
template<int OMODE>
__global__ __launch_bounds__(256, 4) void gemm_bt_kernel(
    const bf16* __restrict__ A, const bf16* __restrict__ B, void* __restrict__ C,
    const float* __restrict__ bias_m, const float* __restrict__ bias_n,
    const float* __restrict__ resid, float* __restrict__ rspart, float alpha, int K,
    int lda, int ldb, int ldc,
    long long sA, long long sB, long long sC, long long sR) {
  unsigned bxi, byi, bz;
  xcd_swz(bxi, byi, bz);
  A += (size_t)bz * sA;
  B += (size_t)bz * sB;
  const int m0 = bxi * 128, n0 = byi * 128;

  __shared__ bf16 ldsA[128 * 64];
  __shared__ bf16 ldsB[128 * 64];

  const int t = threadIdx.x;
  const int lane = t & 63, wv = t >> 6;
  const int wr = (wv >> 1) * 64, wc = (wv & 1) * 64;

  const int r0 = t >> 3;
  const int cb = ((t & 7) << 4) ^ ((r0 & 7) << 4);
  const bf16* gA = A + (size_t)(m0 + r0) * lda + (cb >> 1);
  const bf16* gB = B + (size_t)(n0 + r0) * ldb + (cb >> 1);
  bf16* lA = ldsA + t * 8;
  bf16* lB = ldsB + t * 8;

  const int arow = wr + (lane & 15);
  const int brow = wc + (lane & 15);
  const int kb   = (lane >> 4) * 16;

  f32x4 acc[4][4] = {};

  for (int k0 = 0; k0 < K; k0 += 64) {
    #pragma unroll
    for (int i = 0; i < 4; i++) {
      async16(gA + (size_t)i * 32 * lda + k0, lA + i * 2048);
      async16(gB + (size_t)i * 32 * ldb + k0, lB + i * 2048);
    }
    __syncthreads();
    #pragma unroll
    for (int ks = 0; ks < 2; ks++) {
      bf16x8 af[4], bfr[4];
      #pragma unroll
      for (int f = 0; f < 4; f++) {
        int ra = arow + f * 16;
        af[f] = *reinterpret_cast<const bf16x8*>(
            reinterpret_cast<const char*>(ldsA) + ra * 128 + ((ks * 64 + kb) ^ ((ra & 7) << 4)));
        int rb = brow + f * 16;
        bfr[f] = *reinterpret_cast<const bf16x8*>(
            reinterpret_cast<const char*>(ldsB) + rb * 128 + ((ks * 64 + kb) ^ ((rb & 7) << 4)));
      }
      #pragma unroll
      for (int fm = 0; fm < 4; fm++)
        #pragma unroll
        for (int fn = 0; fn < 4; fn++)
          acc[fm][fn] = __builtin_amdgcn_mfma_f32_16x16x32_bf16(af[fm], bfr[fn], acc[fm][fn], 0, 0, 0);
    }
    __syncthreads();
  }

  #pragma unroll
  for (int fm = 0; fm < 4; fm++) {
    #pragma unroll
    for (int j = 0; j < 4; j++) {
      int gm = m0 + wr + fm * 16 + (lane >> 4) * 4 + j;
      if (OMODE == 2) {
        float rsum = 0.f;
        #pragma unroll
        for (int fn = 0; fn < 4; fn++) {
          int gn = n0 + wc + fn * 16 + (lane & 15);
          float e = __expf(acc[fm][fn][j] * alpha);
          rsum += e;
          reinterpret_cast<bf16*>(C)[(size_t)bz * sC + (size_t)gm * ldc + gn] = __float2bfloat16(e);
        }
        rsum += __shfl_xor(rsum, 1);
        rsum += __shfl_xor(rsum, 2);
        rsum += __shfl_xor(rsum, 4);
        rsum += __shfl_xor(rsum, 8);
        if ((lane & 15) == 0)
          rspart[(((size_t)bz * 4096 + gm) << 6) + byi * 2 + (wv & 1)] = rsum;
      } else {
        float bm = bias_m ? bias_m[gm] : 0.f;
        #pragma unroll
        for (int fn = 0; fn < 4; fn++) {
          int gn = n0 + wc + fn * 16 + (lane & 15);
          float vv = acc[fm][fn][j] * alpha + bm;
          if (bias_n) vv += bias_n[gn];
          if (resid)  vv += resid[(size_t)bz * sR + (size_t)gm * ldc + gn];
          if (OMODE == 1)
            reinterpret_cast<bf16*>(C)[(size_t)bz * sC + (size_t)gm * ldc + gn] = __float2bfloat16(vv);
          else
            reinterpret_cast<float*>(C)[(size_t)bz * sC + (size_t)gm * ldc + gn] = vv;
        }
      }
    }
  }
}

// ---------------- rowsum[r] = sum of 64 partials ----------------
__global__ __launch_bounds__(256) void rowsum_sum_kernel(const float* __restrict__ part,
                                                         float* __restrict__ rowsum) {
  int r = blockIdx.x * 256 + threadIdx.x;
  const float4* p = reinterpret_cast<const float4*>(part + ((size_t)r << 6));
  float s = 0.f;
  #pragma unroll
  for (int i = 0; i < 16; i++) {
    float4 v = p[i];
    s += v.x + v.y + v.z + v.w;
  }
  rowsum[r] = s;
}

// ---------------- PV with split-K=2, normalized by 1/rowsum --------------------
// split_only=0: z -> (b = z>>1, s = z&1). split_only=1: b=0 (pointers pre-offset), s=z.
__global__ __launch_bounds__(256, 4) void pv_split_kernel(
    const bf16* __restrict__ Sb, const bf16* __restrict__ vb,
    const float* __restrict__ rowsum,
    long long sS, long long sV, Ptr4 slots, int split_only) {
  unsigned bxi, byi, bz;
  xcd_swz(bxi, byi, bz);
  const int z = bz;
  const int b = split_only ? 0 : (z >> 1);
  const int s = split_only ? z : (z & 1);
  const bf16* A = Sb + (size_t)b * sS + s * 2048;
  const bf16* B = vb + (size_t)b * sV + s * 2048;
  const float* rs = rowsum + b * 4096;
  bf16* Cp = (bf16*)((&slots.p0)[z]);
  const int m0 = bxi * 128, n0 = byi * 128;

  __shared__ bf16 ldsA[128 * 64];
  __shared__ bf16 ldsB[128 * 64];

  const int t = threadIdx.x;
  const int lane = t & 63, wv = t >> 6;
  const int wr = (wv >> 1) * 64, wc = (wv & 1) * 64;

  const int r0 = t >> 3;
  const int cb = ((t & 7) << 4) ^ ((r0 & 7) << 4);
  const bf16* gA = A + (size_t)(m0 + r0) * 4096 + (cb >> 1);
  const bf16* gB = B + (size_t)(n0 + r0) * 4096 + (cb >> 1);
  bf16* lA = ldsA + t * 8;
  bf16* lB = ldsB + t * 8;

  const int arow = wr + (lane & 15);
  const int brow = wc + (lane & 15);
  const int kb   = (lane >> 4) * 16;

  f32x4 acc[4][4] = {};

  for (int k0 = 0; k0 < 2048; k0 += 64) {
    #pragma unroll
    for (int i = 0; i < 4; i++) {
      async16(gA + (size_t)i * 32 * 4096 + k0, lA + i * 2048);
      async16(gB + (size_t)i * 32 * 4096 + k0, lB + i * 2048);
    }
    __syncthreads();
    #pragma unroll
    for (int ks = 0; ks < 2; ks++) {
      bf16x8 af[4], bfr[4];
      #pragma unroll
      for (int f = 0; f < 4; f++) {
        int ra = arow + f * 16;
        af[f] = *reinterpret_cast<const bf16x8*>(
            reinterpret_cast<const char*>(ldsA) + ra * 128 + ((ks * 64 + kb) ^ ((ra & 7) << 4)));
        int rb = brow + f * 16;
        bfr[f] = *reinterpret_cast<const bf16x8*>(
            reinterpret_cast<const char*>(ldsB) + rb * 128 + ((ks * 64 + kb) ^ ((rb & 7) << 4)));
      }
      #pragma unroll
      for (int fm = 0; fm < 4; fm++)
        #pragma unroll
        for (int fn = 0; fn < 4; fn++)
          acc[fm][fn] = __builtin_amdgcn_mfma_f32_16x16x32_bf16(af[fm], bfr[fn], acc[fm][fn], 0, 0, 0);
    }
    __syncthreads();
  }

  #pragma unroll
  for (int fm = 0; fm < 4; fm++) {
    #pragma unroll
    for (int j = 0; j < 4; j++) {
      int gm = m0 + wr + fm * 16 + (lane >> 4) * 4 + j;
      float inv = 1.0f / rs[gm];
      #pragma unroll
      for (int fn = 0; fn < 4; fn++) {
        int gn = n0 + wc + fn * 16 + (lane & 15);
        Cp[(size_t)gm * 512 + gn] = __float2bfloat16(acc[fm][fn][j] * inv);
      }
    }
  }
}

// ---------------- dst[i] += src[i] (bf16) ----------------
__global__ __launch_bounds__(256) void reduce_add_kernel(bf16* __restrict__ dst,
                                                         const bf16* __restrict__ src, int n) {
  int i = (blockIdx.x * 256 + threadIdx.x) * 8;
  if (i + 7 < n) {
    bf16x8 a = *reinterpret_cast<const bf16x8*>(dst + i);
    bf16x8 b = *reinterpret_cast<const bf16x8*>(src + i);
    bf16x8 r;
    #pragma unroll
    for (int j = 0; j < 8; j++) r[j] = f2bfb(bfb2f(a[j]) + bfb2f(b[j]));
    *reinterpret_cast<bf16x8*>(dst + i) = r;
  }
}

extern "C" void kernel_launch(void* const* d_in, const int* in_sizes, int n_in,
                              void* d_out, int out_size, void* d_ws, size_t ws_size,
                              hipStream_t stream) {
  const float* x     = (const float*)d_in[0];
  const float* gamma = (const float*)d_in[1];
  const float* beta  = (const float*)d_in[2];
  const float* wq    = (const float*)d_in[3];
  const float* bq    = (const float*)d_in[4];
  const float* wk    = (const float*)d_in[5];
  const float* bk    = (const float*)d_in[6];
  const float* wv    = (const float*)d_in[7];
  const float* bv    = (const float*)d_in[8];
  const float* wp    = (const float*)d_in[9];
  const float* bp    = (const float*)d_in[10];
  float* out = (float*)d_out;

  char* w = (char*)d_ws;
  size_t off = 0;
  float* stats  = (float*)(w + off);   off += 4096;
  float* bqk    = (float*)(w + off);   off += 4096;
  float* rowsum = (float*)(w + off);   off += 32768;                   // [2][4096] f32
  float* rspart = (float*)(w + off);   off += (size_t)2 * 4096 * 64 * 4;  // [2][4096][64] f32
  bf16* wqkb = (bf16*)(w + off);       off += (size_t)1024 * 512 * 2;  // [wq;wk] then wv, wp
  bf16* wvb  = (bf16*)(w + off);       off += (size_t)512 * 512 * 2;
  bf16* wpb  = (bf16*)(w + off);       off += (size_t)512 * 512 * 2;
  bf16* h    = (bf16*)(w + off);       off += (size_t)2 * NPX * CCH * 2;
  bf16* qk   = (bf16*)(w + off);       off += (size_t)2 * NPX * 1024 * 2;
  bf16* v    = (bf16*)(w + off);       off += (size_t)2 * NPX * CCH * 2;
  bf16* o    = (bf16*)(w + off);       off += (size_t)2 * NPX * CCH * 2;
  bf16* S    = (bf16*)(w + off);
  size_t need_big = off + (size_t)2 * NPX * NPX * 2;
  const bool big = ws_size >= need_big;

  const long long sBN = (long long)NPX * CCH;      // 4096*512
  const long long sQK = (long long)NPX * 1024;     // 4096*1024
  const long long sS  = (long long)NPX * NPX;      // 4096*4096
  const float scale = 0.04419417382415922f;        // 512^-0.5

  convert_weights_kernel<<<1024, 256, 0, stream>>>(wq, wk, wv, wp, bq, bk, wqkb, bqk);
  gn_stats_kernel<<<64, 256, 0, stream>>>(x, stats);
  gn_apply_kernel<<<dim3(8, 64, 2), 256, 0, stream>>>(x, stats, gamma, beta, h);

  // qk[n][0..1024) = h[n][:] @ [wq;wk]^T + [bq;bk]   (M=4096, N=1024, K=512)
  gemm_bt_kernel<1><<<dim3(32, 8, 2), 256, 0, stream>>>(h, wqkb, qk, nullptr, bqk, nullptr,
      nullptr, 1.f, 512, 512, 512, 1024, sBN, 0, sQK, 0);
  // v[c][n] = wv[c][:] @ h[n][:] + bv[c]             (M=512, N=4096, K=512)
  gemm_bt_kernel<1><<<dim3(4, 32, 2), 256, 0, stream>>>(wvb, h, v, bv, nullptr, nullptr,
      nullptr, 1.f, 512, 512, 512, 4096, 0, sBN, sBN, 0);

  if (big) {
    // P[b][i][j] = exp(scale * q_i . k_j), partial rowsums stored (both batches)
    gemm_bt_kernel<2><<<dim3(32, 32, 2), 256, 0, stream>>>(qk, qk + 512, S,
        nullptr, nullptr, nullptr, rspart, scale, 512, 1024, 1024, 4096, sQK, sQK, sS, 0);
    rowsum_sum_kernel<<<32, 256, 0, stream>>>(rspart, rowsum);
    // PV split-K=2, normalized partials -> {h, o_b0, qk_lo, o_b1}
    Ptr4 slots{h, o, qk, o + sBN};
    pv_split_kernel<<<dim3(32, 4, 4), 256, 0, stream>>>(S, v, rowsum, sS, sBN, slots, 0);
    reduce_add_kernel<<<1024, 256, 0, stream>>>(o, h, NPX * CCH);
    reduce_add_kernel<<<1024, 256, 0, stream>>>(o + sBN, qk, NPX * CCH);
  } else {
    for (int b = 0; b < 2; b++) {
      gemm_bt_kernel<2><<<dim3(32, 32, 1), 256, 0, stream>>>(qk + b * sQK, qk + b * sQK + 512, S,
          nullptr, nullptr, nullptr, rspart, scale, 512, 1024, 1024, 4096, 0, 0, 0, 0);
      rowsum_sum_kernel<<<16, 256, 0, stream>>>(rspart, rowsum + b * 4096);
      Ptr4 slots{h, o + b * sBN, h, h};
      pv_split_kernel<<<dim3(32, 4, 2), 256, 0, stream>>>(S, v + b * sBN, rowsum + b * 4096,
          0, 0, slots, 1);
      reduce_add_kernel<<<1024, 256, 0, stream>>>(o + b * sBN, h, NPX * CCH);
    }
  }

  // out[c][n] = wp[c][:] @ o[n][:] + bp[c] + x       (M=512, N=4096, K=512)
  gemm_bt_kernel<0><<<dim3(4, 32, 2), 256, 0, stream>>>(wpb, o, out, bp, nullptr, x,
      nullptr, 1.f, 512, 512, 512, 4096, 0, sBN, sBN, sBN);
}

// Round 6
// 273.916 us; speedup vs baseline: 1.4826x; 1.0459x over previous
//
#include <hip/hip_runtime.h>
#include <hip/hip_bf16.h>

using bf16 = __hip_bfloat16;
typedef __attribute__((ext_vector_type(4))) float f32x4;
typedef __attribute__((ext_vector_type(8))) short bf16x8;

#define NPX 4096
#define CCH 512

struct Ptr4 { void* p0; void* p1; void* p2; void* p3; };

// Runtime GEMM parameter block (uniform per sub-grid).
struct GemmP {
  const bf16* A; const bf16* B; void* C;
  const float* bias_m; const float* bias_n; const float* resid;
  float* rspart;
  float alpha; int K;
  int lda, ldb, ldc;
  long long sA, sB, sC, sR;
  int gx, gy;      // sub-grid tile dims (z implied by block count)
  int omode;       // 0 = f32 out (+bias/resid), 1 = bf16 out (+bias), 2 = exp-out + rspart
};

__device__ __forceinline__ void async16(const bf16* g, bf16* l) {
  __builtin_amdgcn_global_load_lds((const __attribute__((address_space(1))) void*)g,
                                   (__attribute__((address_space(3))) void*)l, 16, 0, 0);
}

__device__ __forceinline__ float bfb2f(short s) {
  unsigned u = ((unsigned)(unsigned short)s) << 16;
  float f;
  __builtin_memcpy(&f, &u, 4);
  return f;
}

__device__ __forceinline__ short f2bfb(float f) {
  bf16 h = __float2bfloat16(f);
  short s;
  __builtin_memcpy(&s, &h, 2);
  return s;
}

// ---------------- prep: weight convert + bias pack + GN partial sums ----------
// blocks [0,1024): convert 1M weight floats to bf16 (+ bqk pack in block 0)
// blocks [1024,1536): GN partial sums, 8192 floats each -> pstats[512][2]
__global__ __launch_bounds__(256) void prep_kernel(
    const float* __restrict__ wq, const float* __restrict__ wk,
    const float* __restrict__ wv, const float* __restrict__ wp,
    const float* __restrict__ bq, const float* __restrict__ bk,
    const float* __restrict__ x,
    bf16* __restrict__ wout, float* __restrict__ bqk, float* __restrict__ pstats) {
  int bid = blockIdx.x;
  int t = threadIdx.x;
  if (bid < 1024) {
    int tid = bid * 256 + t;
    int i = tid * 4;  // [0, 1M)
    int seg = i >> 18;
    const float* in = seg == 0 ? wq : seg == 1 ? wk : seg == 2 ? wv : wp;
    float4 v = *reinterpret_cast<const float4*>(in + (i & 262143));
    wout[i]     = __float2bfloat16(v.x);
    wout[i + 1] = __float2bfloat16(v.y);
    wout[i + 2] = __float2bfloat16(v.z);
    wout[i + 3] = __float2bfloat16(v.w);
    if (tid < 256) {
      int j = tid * 4;
      const float* bsrc = j < 512 ? bq : bk;
      float4 b = *reinterpret_cast<const float4*>(bsrc + (j & 511));
      *reinterpret_cast<float4*>(bqk + j) = b;
    }
  } else {
    int bp = bid - 1024;  // [0,512): (b,g) = bp>>3, chunk = bp&7
    const float* p = x + (size_t)bp * 8192;
    float s = 0.f, s2 = 0.f;
    #pragma unroll
    for (int j = 0; j < 8; j++) {
      float4 v = *reinterpret_cast<const float4*>(p + j * 1024 + t * 4);
      s  += v.x + v.y + v.z + v.w;
      s2 += v.x * v.x + v.y * v.y + v.z * v.z + v.w * v.w;
    }
    #pragma unroll
    for (int off = 32; off >= 1; off >>= 1) {
      s  += __shfl_xor(s, off);
      s2 += __shfl_xor(s2, off);
    }
    __shared__ float ls[8];
    int wv_ = t >> 6;
    if ((t & 63) == 0) { ls[wv_ * 2] = s; ls[wv_ * 2 + 1] = s2; }
    __syncthreads();
    if (t == 0) {
      pstats[bp * 2]     = ls[0] + ls[2] + ls[4] + ls[6];
      pstats[bp * 2 + 1] = ls[1] + ls[3] + ls[5] + ls[7];
    }
  }
}

// ---------------- GroupNorm apply + transpose to [n][c] bf16 -------------------
// Computes final group stats from pstats (8 partials per group) in-block.
__global__ __launch_bounds__(256) void gn_apply_kernel(const float* __restrict__ x,
    const float* __restrict__ pstats, const float* __restrict__ gamma,
    const float* __restrict__ beta, bf16* __restrict__ h) {
  __shared__ float tile[64][65];
  __shared__ float mr[4][2];
  int b  = blockIdx.z;
  int c0 = blockIdx.x * 64, n0 = blockIdx.y * 64;
  int t  = threadIdx.x;
  if (t < 4) {
    int g = (c0 >> 4) + t;
    float S = 0.f, S2 = 0.f;
    #pragma unroll
    for (int k2 = 0; k2 < 8; k2++) {
      S  += pstats[((b * 32 + g) * 8 + k2) * 2];
      S2 += pstats[((b * 32 + g) * 8 + k2) * 2 + 1];
    }
    float mean = S * (1.f / 65536.f);
    float var  = S2 * (1.f / 65536.f) - mean * mean;
    mr[t][0] = mean;
    mr[t][1] = rsqrtf(var + 1e-6f);
  }
  __syncthreads();
  int cl = t >> 6, nl = t & 63;
  #pragma unroll
  for (int i = 0; i < 16; i++) {
    int c = c0 + cl + i * 4;
    float v = x[((size_t)b * CCH + c) * NPX + n0 + nl];
    int gi = (cl + i * 4) >> 4;
    tile[cl + i * 4][nl] = (v - mr[gi][0]) * mr[gi][1] * gamma[c] + beta[c];
  }
  __syncthreads();
  #pragma unroll
  for (int i = 0; i < 16; i++) {
    int n = cl + i * 4;
    int c = nl;
    h[((size_t)b * NPX + n0 + n) * CCH + c0 + c] = __float2bfloat16(tile[c][n]);
  }
}

// ---------------- generic B^T GEMM, 1-D grid, dual param blocks ----------------
// C[m][n] = f(alpha * sum_k A[m][k] B[n][k]); XCD-swizzled flat id; block < nb0
// uses p0, else p1 (fused independent GEMMs co-schedule across the chip).
__global__ __launch_bounds__(256, 4) void gemm_any_kernel(GemmP p0, GemmP p1, unsigned nb0) {
  unsigned nwg = gridDim.x;
  unsigned flat = blockIdx.x;
  unsigned swz = (flat & 7) * (nwg >> 3) + (flat >> 3);
  GemmP p = swz < nb0 ? p0 : p1;
  unsigned local = swz < nb0 ? swz : swz - nb0;
  unsigned bxi = local % p.gx;
  unsigned tmp = local / p.gx;
  unsigned byi = tmp % p.gy;
  unsigned bz  = tmp / p.gy;

  const bf16* A = p.A + (size_t)bz * p.sA;
  const bf16* B = p.B + (size_t)bz * p.sB;
  const int m0 = bxi * 128, n0 = byi * 128;

  __shared__ bf16 ldsA[128 * 64];
  __shared__ bf16 ldsB[128 * 64];

  const int t = threadIdx.x;
  const int lane = t & 63, wv = t >> 6;
  const int wr = (wv >> 1) * 64, wc = (wv & 1) * 64;

  const int r0 = t >> 3;
  const int cb = ((t & 7) << 4) ^ ((r0 & 7) << 4);
  const bf16* gA = A + (size_t)(m0 + r0) * p.lda + (cb >> 1);
  const bf16* gB = B + (size_t)(n0 + r0) * p.ldb + (cb >> 1);
  bf16* lA = ldsA + t * 8;
  bf16* lB = ldsB + t * 8;

  const int arow = wr + (lane & 15);
  const int brow = wc + (lane & 15);
  const int kb   = (lane >> 4) * 16;

  f32x4 acc[4][4] = {};

  for (int k0 = 0; k0 < p.K; k0 += 64) {
    #pragma unroll
    for (int i = 0; i < 4; i++) {
      async16(gA + (size_t)i * 32 * p.lda + k0, lA + i * 2048);
      async16(gB + (size_t)i * 32 * p.ldb + k0, lB + i * 2048);
    }
    __syncthreads();
    #pragma unroll
    for (int ks = 0; ks < 2; ks++) {
      bf16x8 af[4], bfr[4];
      #pragma unroll
      for (int f = 0; f < 4; f++) {
        int ra = arow + f * 16;
        af[f] = *reinterpret_cast<const bf16x8*>(
            reinterpret_cast<const char*>(ldsA) + ra * 128 + ((ks * 64 + kb) ^ ((ra & 7) << 4)));
        int rb = brow + f * 16;
        bfr[f] = *reinterpret_cast<const bf16x8*>(
            reinterpret_cast<const char*>(ldsB) + rb * 128 + ((ks * 64 + kb) ^ ((rb & 7) << 4)));
      }
      #pragma unroll
      for (int fm = 0; fm < 4; fm++)
        #pragma unroll
        for (int fn = 0; fn < 4; fn++)
          acc[fm][fn] = __builtin_amdgcn_mfma_f32_16x16x32_bf16(af[fm], bfr[fn], acc[fm][fn], 0, 0, 0);
    }
    __syncthreads();
  }

  #pragma unroll
  for (int fm = 0; fm < 4; fm++) {
    #pragma unroll
    for (int j = 0; j < 4; j++) {
      int gm = m0 + wr + fm * 16 + (lane >> 4) * 4 + j;
      if (p.omode == 2) {
        float rsum = 0.f;
        #pragma unroll
        for (int fn = 0; fn < 4; fn++) {
          int gn = n0 + wc + fn * 16 + (lane & 15);
          float e = __expf(acc[fm][fn][j] * p.alpha);
          rsum += e;
          reinterpret_cast<bf16*>(p.C)[(size_t)bz * p.sC + (size_t)gm * p.ldc + gn] = __float2bfloat16(e);
        }
        rsum += __shfl_xor(rsum, 1);
        rsum += __shfl_xor(rsum, 2);
        rsum += __shfl_xor(rsum, 4);
        rsum += __shfl_xor(rsum, 8);
        if ((lane & 15) == 0)
          p.rspart[(((size_t)bz * 4096 + gm) << 6) + byi * 2 + (wv & 1)] = rsum;
      } else {
        float bm = p.bias_m ? p.bias_m[gm] : 0.f;
        #pragma unroll
        for (int fn = 0; fn < 4; fn++) {
          int gn = n0 + wc + fn * 16 + (lane & 15);
          float vv = acc[fm][fn][j] * p.alpha + bm;
          if (p.bias_n) vv += p.bias_n[gn];
          if (p.resid)  vv += p.resid[(size_t)bz * p.sR + (size_t)gm * p.ldc + gn];
          if (p.omode == 1)
            reinterpret_cast<bf16*>(p.C)[(size_t)bz * p.sC + (size_t)gm * p.ldc + gn] = __float2bfloat16(vv);
          else
            reinterpret_cast<float*>(p.C)[(size_t)bz * p.sC + (size_t)gm * p.ldc + gn] = vv;
        }
      }
    }
  }
}

// ---------------- PV with split-K=2, rowsum summed in-block from rspart --------
// split_only=0: z -> (b = z>>1, s = z&1). split_only=1: b=0 (pointers pre-offset), s=z.
__global__ __launch_bounds__(256, 4) void pv_split_kernel(
    const bf16* __restrict__ Sb, const bf16* __restrict__ vb,
    const float* __restrict__ rspart,
    long long sS, long long sV, Ptr4 slots, int split_only) {
  unsigned nx = gridDim.x, ny = gridDim.y;
  unsigned flat = (blockIdx.z * ny + blockIdx.y) * nx + blockIdx.x;
  unsigned nwg = nx * ny * gridDim.z;
  unsigned swz = (flat & 7) * (nwg >> 3) + (flat >> 3);
  unsigned bxi = swz % nx;
  unsigned tmp = swz / nx;
  unsigned byi = tmp % ny;
  unsigned bz  = tmp / ny;

  const int z = bz;
  const int b = split_only ? 0 : (z >> 1);
  const int s = split_only ? z : (z & 1);
  const bf16* A = Sb + (size_t)b * sS + s * 2048;
  const bf16* B = vb + (size_t)b * sV + s * 2048;
  bf16* Cp = (bf16*)((&slots.p0)[z]);
  const int m0 = bxi * 128, n0 = byi * 128;

  __shared__ bf16 ldsA[128 * 64];
  __shared__ bf16 ldsB[128 * 64];
  __shared__ float rs_lds[128];

  const int t = threadIdx.x;

  // sum the 64 rowsum partials for this block's 128 rows
  if (t < 128) {
    const float4* pp = reinterpret_cast<const float4*>(rspart + (((size_t)b * 4096 + m0 + t) << 6));
    float ssum = 0.f;
    #pragma unroll
    for (int i2 = 0; i2 < 16; i2++) {
      float4 vv = pp[i2];
      ssum += vv.x + vv.y + vv.z + vv.w;
    }
    rs_lds[t] = 1.0f / ssum;
  }

  const int lane = t & 63, wv = t >> 6;
  const int wr = (wv >> 1) * 64, wc = (wv & 1) * 64;

  const int r0 = t >> 3;
  const int cb = ((t & 7) << 4) ^ ((r0 & 7) << 4);
  const bf16* gA = A + (size_t)(m0 + r0) * 4096 + (cb >> 1);
  const bf16* gB = B + (size_t)(n0 + r0) * 4096 + (cb >> 1);
  bf16* lA = ldsA + t * 8;
  bf16* lB = ldsB + t * 8;

  const int arow = wr + (lane & 15);
  const int brow = wc + (lane & 15);
  const int kb   = (lane >> 4) * 16;

  f32x4 acc[4][4] = {};

  for (int k0 = 0; k0 < 2048; k0 += 64) {
    #pragma unroll
    for (int i = 0; i < 4; i++) {
      async16(gA + (size_t)i * 32 * 4096 + k0, lA + i * 2048);
      async16(gB + (size_t)i * 32 * 4096 + k0, lB + i * 2048);
    }
    __syncthreads();
    #pragma unroll
    for (int ks = 0; ks < 2; ks++) {
      bf16x8 af[4], bfr[4];
      #pragma unroll
      for (int f = 0; f < 4; f++) {
        int ra = arow + f * 16;
        af[f] = *reinterpret_cast<const bf16x8*>(
            reinterpret_cast<const char*>(ldsA) + ra * 128 + ((ks * 64 + kb) ^ ((ra & 7) << 4)));
        int rb = brow + f * 16;
        bfr[f] = *reinterpret_cast<const bf16x8*>(
            reinterpret_cast<const char*>(ldsB) + rb * 128 + ((ks * 64 + kb) ^ ((rb & 7) << 4)));
      }
      #pragma unroll
      for (int fm = 0; fm < 4; fm++)
        #pragma unroll
        for (int fn = 0; fn < 4; fn++)
          acc[fm][fn] = __builtin_amdgcn_mfma_f32_16x16x32_bf16(af[fm], bfr[fn], acc[fm][fn], 0, 0, 0);
    }
    __syncthreads();
  }

  #pragma unroll
  for (int fm = 0; fm < 4; fm++) {
    #pragma unroll
    for (int j = 0; j < 4; j++) {
      int lrow = wr + fm * 16 + (lane >> 4) * 4 + j;
      float inv = rs_lds[lrow];
      int gm = m0 + lrow;
      #pragma unroll
      for (int fn = 0; fn < 4; fn++) {
        int gn = n0 + wc + fn * 16 + (lane & 15);
        Cp[(size_t)gm * 512 + gn] = __float2bfloat16(acc[fm][fn][j] * inv);
      }
    }
  }
}

// ---------------- merged split-K reduce: o[0..2M) += h, o[2M..4M) += qk --------
__global__ __launch_bounds__(256) void reduce_add2_kernel(bf16* __restrict__ o,
    const bf16* __restrict__ hsrc, const bf16* __restrict__ qksrc) {
  int i = (blockIdx.x * 256 + threadIdx.x) * 8;
  const bf16* src = i < 2097152 ? hsrc + i : qksrc + (i - 2097152);
  bf16x8 a = *reinterpret_cast<const bf16x8*>(o + i);
  bf16x8 b = *reinterpret_cast<const bf16x8*>(src);
  bf16x8 r;
  #pragma unroll
  for (int j = 0; j < 8; j++) r[j] = f2bfb(bfb2f(a[j]) + bfb2f(b[j]));
  *reinterpret_cast<bf16x8*>(o + i) = r;
}

// ---------------- single-range reduce (fallback path) ----------------
__global__ __launch_bounds__(256) void reduce_add_kernel(bf16* __restrict__ dst,
                                                         const bf16* __restrict__ src, int n) {
  int i = (blockIdx.x * 256 + threadIdx.x) * 8;
  if (i + 7 < n) {
    bf16x8 a = *reinterpret_cast<const bf16x8*>(dst + i);
    bf16x8 b = *reinterpret_cast<const bf16x8*>(src + i);
    bf16x8 r;
    #pragma unroll
    for (int j = 0; j < 8; j++) r[j] = f2bfb(bfb2f(a[j]) + bfb2f(b[j]));
    *reinterpret_cast<bf16x8*>(dst + i) = r;
  }
}

extern "C" void kernel_launch(void* const* d_in, const int* in_sizes, int n_in,
                              void* d_out, int out_size, void* d_ws, size_t ws_size,
                              hipStream_t stream) {
  const float* x     = (const float*)d_in[0];
  const float* gamma = (const float*)d_in[1];
  const float* beta  = (const float*)d_in[2];
  const float* wq    = (const float*)d_in[3];
  const float* bq    = (const float*)d_in[4];
  const float* wk    = (const float*)d_in[5];
  const float* bk    = (const float*)d_in[6];
  const float* wv    = (const float*)d_in[7];
  const float* bv    = (const float*)d_in[8];
  const float* wp    = (const float*)d_in[9];
  const float* bp    = (const float*)d_in[10];
  float* out = (float*)d_out;

  char* w = (char*)d_ws;
  size_t off = 0;
  float* pstats = (float*)(w + off);   off += 4096;                        // [512][2]
  float* bqk    = (float*)(w + off);   off += 4096;
  float* rspart = (float*)(w + off);   off += (size_t)2 * 4096 * 64 * 4;   // [2][4096][64]
  bf16* wqkb = (bf16*)(w + off);       off += (size_t)1024 * 512 * 2;      // [wq;wk] then wv, wp
  bf16* wvb  = (bf16*)(w + off);       off += (size_t)512 * 512 * 2;
  bf16* wpb  = (bf16*)(w + off);       off += (size_t)512 * 512 * 2;
  bf16* h    = (bf16*)(w + off);       off += (size_t)2 * NPX * CCH * 2;
  bf16* qk   = (bf16*)(w + off);       off += (size_t)2 * NPX * 1024 * 2;
  bf16* v    = (bf16*)(w + off);       off += (size_t)2 * NPX * CCH * 2;
  bf16* o    = (bf16*)(w + off);       off += (size_t)2 * NPX * CCH * 2;
  bf16* S    = (bf16*)(w + off);
  size_t need_big = off + (size_t)2 * NPX * NPX * 2;
  const bool big = ws_size >= need_big;

  const long long sBN = (long long)NPX * CCH;      // 4096*512
  const long long sQK = (long long)NPX * 1024;     // 4096*1024
  const long long sS  = (long long)NPX * NPX;      // 4096*4096
  const float scale = 0.04419417382415922f;        // 512^-0.5

  prep_kernel<<<1536, 256, 0, stream>>>(wq, wk, wv, wp, bq, bk, x, wqkb, bqk, pstats);
  gn_apply_kernel<<<dim3(8, 64, 2), 256, 0, stream>>>(x, pstats, gamma, beta, h);

  // fused launch: qkv-proj (512 blocks) + v-proj (256 blocks)
  GemmP pqkv = {h, wqkb, qk, nullptr, bqk, nullptr, nullptr,
                1.f, 512, 512, 512, 1024, sBN, 0, sQK, 0, 32, 8, 1};
  GemmP pv   = {wvb, h, v, bv, nullptr, nullptr, nullptr,
                1.f, 512, 512, 512, 4096, 0, sBN, sBN, 0, 4, 32, 1};
  gemm_any_kernel<<<768, 256, 0, stream>>>(pqkv, pv, 512);

  if (big) {
    // P[b][i][j] = exp(scale * q_i . k_j), partial rowsums stored (both batches)
    GemmP ps = {qk, qk + 512, S, nullptr, nullptr, nullptr, rspart,
                scale, 512, 1024, 1024, 4096, sQK, sQK, sS, 0, 32, 32, 2};
    gemm_any_kernel<<<2048, 256, 0, stream>>>(ps, ps, 2048);
    // PV split-K=2 (rowsum summed in-block): partials -> {h, o_b0, qk_lo, o_b1}
    Ptr4 slots{h, o, qk, o + sBN};
    pv_split_kernel<<<dim3(32, 4, 4), 256, 0, stream>>>(S, v, rspart, sS, sBN, slots, 0);
    reduce_add2_kernel<<<2048, 256, 0, stream>>>(o, h, qk);
  } else {
    for (int b = 0; b < 2; b++) {
      GemmP ps = {qk + b * sQK, qk + b * sQK + 512, S, nullptr, nullptr, nullptr,
                  rspart + ((size_t)b << 18),
                  scale, 512, 1024, 1024, 4096, 0, 0, 0, 0, 32, 32, 2};
      gemm_any_kernel<<<1024, 256, 0, stream>>>(ps, ps, 1024);
      Ptr4 slots{h, o + b * sBN, h, h};
      pv_split_kernel<<<dim3(32, 4, 2), 256, 0, stream>>>(S, v + b * sBN,
          rspart + ((size_t)b << 18), 0, 0, slots, 1);
      reduce_add_kernel<<<1024, 256, 0, stream>>>(o + b * sBN, h, 2097152);
    }
  }

  // out[c][n] = wp[c][:] @ o[n][:] + bp[c] + x       (M=512, N=4096, K=512)
  GemmP po = {wpb, o, out, bp, nullptr, x, nullptr,
              1.f, 512, 512, 512, 4096, 0, sBN, sBN, sBN, 4, 32, 0};
  gemm_any_kernel<<<256, 256, 0, stream>>>(po, po, 256);
}

// Round 7
// 268.671 us; speedup vs baseline: 1.5115x; 1.0195x over previous
//
#include <hip/hip_runtime.h>
#include <hip/hip_bf16.h>

using bf16 = __hip_bfloat16;
typedef __attribute__((ext_vector_type(4))) float f32x4;
typedef __attribute__((ext_vector_type(8))) short bf16x8;

#define NPX 4096
#define CCH 512

struct Ptr8 { void* p[8]; };

// Runtime GEMM parameter block (uniform per sub-grid).
struct GemmP {
  const bf16* A; const bf16* B; void* C;
  const float* bias_m; const float* bias_n; const float* resid;
  float* rspart;
  float alpha; int K;
  int lda, ldb, ldc;
  long long sA, sB, sC, sR;
  int gx, gy;      // sub-grid tile dims (z implied by block count)
  int omode;       // 0 = f32 out (+bias/resid), 1 = bf16 out (+bias), 2 = exp-out + rspart
};

__device__ __forceinline__ void async16(const bf16* g, bf16* l) {
  __builtin_amdgcn_global_load_lds((const __attribute__((address_space(1))) void*)g,
                                   (__attribute__((address_space(3))) void*)l, 16, 0, 0);
}

__device__ __forceinline__ float bfb2f(short s) {
  unsigned u = ((unsigned)(unsigned short)s) << 16;
  float f;
  __builtin_memcpy(&f, &u, 4);
  return f;
}

__device__ __forceinline__ short f2bfb(float f) {
  bf16 h = __float2bfloat16(f);
  short s;
  __builtin_memcpy(&s, &h, 2);
  return s;
}

// ---------------- prep: weight convert + bias pack + GN partial sums ----------
__global__ __launch_bounds__(256) void prep_kernel(
    const float* __restrict__ wq, const float* __restrict__ wk,
    const float* __restrict__ wv, const float* __restrict__ wp,
    const float* __restrict__ bq, const float* __restrict__ bk,
    const float* __restrict__ x,
    bf16* __restrict__ wout, float* __restrict__ bqk, float* __restrict__ pstats) {
  int bid = blockIdx.x;
  int t = threadIdx.x;
  if (bid < 1024) {
    int tid = bid * 256 + t;
    int i = tid * 4;  // [0, 1M)
    int seg = i >> 18;
    const float* in = seg == 0 ? wq : seg == 1 ? wk : seg == 2 ? wv : wp;
    float4 v = *reinterpret_cast<const float4*>(in + (i & 262143));
    wout[i]     = __float2bfloat16(v.x);
    wout[i + 1] = __float2bfloat16(v.y);
    wout[i + 2] = __float2bfloat16(v.z);
    wout[i + 3] = __float2bfloat16(v.w);
    if (tid < 256) {
      int j = tid * 4;
      const float* bsrc = j < 512 ? bq : bk;
      float4 b = *reinterpret_cast<const float4*>(bsrc + (j & 511));
      *reinterpret_cast<float4*>(bqk + j) = b;
    }
  } else {
    int bp = bid - 1024;  // [0,512)
    const float* p = x + (size_t)bp * 8192;
    float s = 0.f, s2 = 0.f;
    #pragma unroll
    for (int j = 0; j < 8; j++) {
      float4 v = *reinterpret_cast<const float4*>(p + j * 1024 + t * 4);
      s  += v.x + v.y + v.z + v.w;
      s2 += v.x * v.x + v.y * v.y + v.z * v.z + v.w * v.w;
    }
    #pragma unroll
    for (int off = 32; off >= 1; off >>= 1) {
      s  += __shfl_xor(s, off);
      s2 += __shfl_xor(s2, off);
    }
    __shared__ float ls[8];
    int wv_ = t >> 6;
    if ((t & 63) == 0) { ls[wv_ * 2] = s; ls[wv_ * 2 + 1] = s2; }
    __syncthreads();
    if (t == 0) {
      pstats[bp * 2]     = ls[0] + ls[2] + ls[4] + ls[6];
      pstats[bp * 2 + 1] = ls[1] + ls[3] + ls[5] + ls[7];
    }
  }
}

// ---------------- GroupNorm apply + transpose to [n][c] bf16 -------------------
__global__ __launch_bounds__(256) void gn_apply_kernel(const float* __restrict__ x,
    const float* __restrict__ pstats, const float* __restrict__ gamma,
    const float* __restrict__ beta, bf16* __restrict__ h) {
  __shared__ float tile[64][65];
  __shared__ float mr[4][2];
  int b  = blockIdx.z;
  int c0 = blockIdx.x * 64, n0 = blockIdx.y * 64;
  int t  = threadIdx.x;
  if (t < 4) {
    int g = (c0 >> 4) + t;
    float S = 0.f, S2 = 0.f;
    #pragma unroll
    for (int k2 = 0; k2 < 8; k2++) {
      S  += pstats[((b * 32 + g) * 8 + k2) * 2];
      S2 += pstats[((b * 32 + g) * 8 + k2) * 2 + 1];
    }
    float mean = S * (1.f / 65536.f);
    float var  = S2 * (1.f / 65536.f) - mean * mean;
    mr[t][0] = mean;
    mr[t][1] = rsqrtf(var + 1e-6f);
  }
  __syncthreads();
  int cl = t >> 6, nl = t & 63;
  #pragma unroll
  for (int i = 0; i < 16; i++) {
    int c = c0 + cl + i * 4;
    float v = x[((size_t)b * CCH + c) * NPX + n0 + nl];
    int gi = (cl + i * 4) >> 4;
    tile[cl + i * 4][nl] = (v - mr[gi][0]) * mr[gi][1] * gamma[c] + beta[c];
  }
  __syncthreads();
  #pragma unroll
  for (int i = 0; i < 16; i++) {
    int n = cl + i * 4;
    int c = nl;
    h[((size_t)b * NPX + n0 + n) * CCH + c0 + c] = __float2bfloat16(tile[c][n]);
  }
}

// ---------------- generic B^T GEMM, 1-D grid, dual param blocks ----------------
__global__ __launch_bounds__(256, 4) void gemm_any_kernel(GemmP p0, GemmP p1, unsigned nb0) {
  unsigned nwg = gridDim.x;
  unsigned flat = blockIdx.x;
  unsigned swz = (flat & 7) * (nwg >> 3) + (flat >> 3);
  GemmP p = swz < nb0 ? p0 : p1;
  unsigned local = swz < nb0 ? swz : swz - nb0;
  unsigned bxi = local % p.gx;
  unsigned tmp = local / p.gx;
  unsigned byi = tmp % p.gy;
  unsigned bz  = tmp / p.gy;

  const bf16* A = p.A + (size_t)bz * p.sA;
  const bf16* B = p.B + (size_t)bz * p.sB;
  const int m0 = bxi * 128, n0 = byi * 128;

  __shared__ bf16 ldsA[128 * 64];
  __shared__ bf16 ldsB[128 * 64];

  const int t = threadIdx.x;
  const int lane = t & 63, wv = t >> 6;
  const int wr = (wv >> 1) * 64, wc = (wv & 1) * 64;

  const int r0 = t >> 3;
  const int cb = ((t & 7) << 4) ^ ((r0 & 7) << 4);
  const bf16* gA = A + (size_t)(m0 + r0) * p.lda + (cb >> 1);
  const bf16* gB = B + (size_t)(n0 + r0) * p.ldb + (cb >> 1);
  bf16* lA = ldsA + t * 8;
  bf16* lB = ldsB + t * 8;

  const int arow = wr + (lane & 15);
  const int brow = wc + (lane & 15);
  const int kb   = (lane >> 4) * 16;

  f32x4 acc[4][4] = {};

  for (int k0 = 0; k0 < p.K; k0 += 64) {
    #pragma unroll
    for (int i = 0; i < 4; i++) {
      async16(gA + (size_t)i * 32 * p.lda + k0, lA + i * 2048);
      async16(gB + (size_t)i * 32 * p.ldb + k0, lB + i * 2048);
    }
    __syncthreads();
    #pragma unroll
    for (int ks = 0; ks < 2; ks++) {
      bf16x8 af[4], bfr[4];
      #pragma unroll
      for (int f = 0; f < 4; f++) {
        int ra = arow + f * 16;
        af[f] = *reinterpret_cast<const bf16x8*>(
            reinterpret_cast<const char*>(ldsA) + ra * 128 + ((ks * 64 + kb) ^ ((ra & 7) << 4)));
        int rb = brow + f * 16;
        bfr[f] = *reinterpret_cast<const bf16x8*>(
            reinterpret_cast<const char*>(ldsB) + rb * 128 + ((ks * 64 + kb) ^ ((rb & 7) << 4)));
      }
      #pragma unroll
      for (int fm = 0; fm < 4; fm++)
        #pragma unroll
        for (int fn = 0; fn < 4; fn++)
          acc[fm][fn] = __builtin_amdgcn_mfma_f32_16x16x32_bf16(af[fm], bfr[fn], acc[fm][fn], 0, 0, 0);
    }
    __syncthreads();
  }

  #pragma unroll
  for (int fm = 0; fm < 4; fm++) {
    #pragma unroll
    for (int j = 0; j < 4; j++) {
      int gm = m0 + wr + fm * 16 + (lane >> 4) * 4 + j;
      if (p.omode == 2) {
        float rsum = 0.f;
        #pragma unroll
        for (int fn = 0; fn < 4; fn++) {
          int gn = n0 + wc + fn * 16 + (lane & 15);
          float e = __expf(acc[fm][fn][j] * p.alpha);
          rsum += e;
          reinterpret_cast<bf16*>(p.C)[(size_t)bz * p.sC + (size_t)gm * p.ldc + gn] = __float2bfloat16(e);
        }
        rsum += __shfl_xor(rsum, 1);
        rsum += __shfl_xor(rsum, 2);
        rsum += __shfl_xor(rsum, 4);
        rsum += __shfl_xor(rsum, 8);
        if ((lane & 15) == 0)
          p.rspart[(((size_t)bz * 4096 + gm) << 6) + byi * 2 + (wv & 1)] = rsum;
      } else {
        float bm = p.bias_m ? p.bias_m[gm] : 0.f;
        #pragma unroll
        for (int fn = 0; fn < 4; fn++) {
          int gn = n0 + wc + fn * 16 + (lane & 15);
          float vv = acc[fm][fn][j] * p.alpha + bm;
          if (p.bias_n) vv += p.bias_n[gn];
          if (p.resid)  vv += p.resid[(size_t)bz * p.sR + (size_t)gm * p.ldc + gn];
          if (p.omode == 1)
            reinterpret_cast<bf16*>(p.C)[(size_t)bz * p.sC + (size_t)gm * p.ldc + gn] = __float2bfloat16(vv);
          else
            reinterpret_cast<float*>(p.C)[(size_t)bz * p.sC + (size_t)gm * p.ldc + gn] = vv;
        }
      }
    }
  }
}

// ---------------- PV with split-K=4, rowsum summed in-block from rspart --------
// mode=0: z -> (b = z>>2, s = z&3). mode=1: b=0 (pointers pre-offset), s=z.
__global__ __launch_bounds__(256, 4) void pv_split_kernel(
    const bf16* __restrict__ Sb, const bf16* __restrict__ vb,
    const float* __restrict__ rspart,
    long long sS, long long sV, Ptr8 slots, int mode) {
  unsigned nx = gridDim.x, ny = gridDim.y;
  unsigned flat = (blockIdx.z * ny + blockIdx.y) * nx + blockIdx.x;
  unsigned nwg = nx * ny * gridDim.z;
  unsigned swz = (flat & 7) * (nwg >> 3) + (flat >> 3);
  unsigned bxi = swz % nx;
  unsigned tmp = swz / nx;
  unsigned byi = tmp % ny;
  unsigned bz  = tmp / ny;

  const int z = bz;
  const int b = mode ? 0 : (z >> 2);
  const int s = mode ? z : (z & 3);
  const bf16* A = Sb + (size_t)b * sS + s * 1024;
  const bf16* B = vb + (size_t)b * sV + s * 1024;
  bf16* Cp = (bf16*)(slots.p[z]);
  const int m0 = bxi * 128, n0 = byi * 128;

  __shared__ bf16 ldsA[128 * 64];
  __shared__ bf16 ldsB[128 * 64];
  __shared__ float rs_lds[128];

  const int t = threadIdx.x;

  // sum the 64 rowsum partials for this block's 128 rows
  if (t < 128) {
    const float4* pp = reinterpret_cast<const float4*>(rspart + (((size_t)b * 4096 + m0 + t) << 6));
    float ssum = 0.f;
    #pragma unroll
    for (int i2 = 0; i2 < 16; i2++) {
      float4 vv = pp[i2];
      ssum += vv.x + vv.y + vv.z + vv.w;
    }
    rs_lds[t] = 1.0f / ssum;
  }

  const int lane = t & 63, wv = t >> 6;
  const int wr = (wv >> 1) * 64, wc = (wv & 1) * 64;

  const int r0 = t >> 3;
  const int cb = ((t & 7) << 4) ^ ((r0 & 7) << 4);
  const bf16* gA = A + (size_t)(m0 + r0) * 4096 + (cb >> 1);
  const bf16* gB = B + (size_t)(n0 + r0) * 4096 + (cb >> 1);
  bf16* lA = ldsA + t * 8;
  bf16* lB = ldsB + t * 8;

  const int arow = wr + (lane & 15);
  const int brow = wc + (lane & 15);
  const int kb   = (lane >> 4) * 16;

  f32x4 acc[4][4] = {};

  for (int k0 = 0; k0 < 1024; k0 += 64) {
    #pragma unroll
    for (int i = 0; i < 4; i++) {
      async16(gA + (size_t)i * 32 * 4096 + k0, lA + i * 2048);
      async16(gB + (size_t)i * 32 * 4096 + k0, lB + i * 2048);
    }
    __syncthreads();
    #pragma unroll
    for (int ks = 0; ks < 2; ks++) {
      bf16x8 af[4], bfr[4];
      #pragma unroll
      for (int f = 0; f < 4; f++) {
        int ra = arow + f * 16;
        af[f] = *reinterpret_cast<const bf16x8*>(
            reinterpret_cast<const char*>(ldsA) + ra * 128 + ((ks * 64 + kb) ^ ((ra & 7) << 4)));
        int rb = brow + f * 16;
        bfr[f] = *reinterpret_cast<const bf16x8*>(
            reinterpret_cast<const char*>(ldsB) + rb * 128 + ((ks * 64 + kb) ^ ((rb & 7) << 4)));
      }
      #pragma unroll
      for (int fm = 0; fm < 4; fm++)
        #pragma unroll
        for (int fn = 0; fn < 4; fn++)
          acc[fm][fn] = __builtin_amdgcn_mfma_f32_16x16x32_bf16(af[fm], bfr[fn], acc[fm][fn], 0, 0, 0);
    }
    __syncthreads();
  }

  #pragma unroll
  for (int fm = 0; fm < 4; fm++) {
    #pragma unroll
    for (int j = 0; j < 4; j++) {
      int lrow = wr + fm * 16 + (lane >> 4) * 4 + j;
      float inv = rs_lds[lrow];
      int gm = m0 + lrow;
      #pragma unroll
      for (int fn = 0; fn < 4; fn++) {
        int gn = n0 + wc + fn * 16 + (lane & 15);
        Cp[(size_t)gm * 512 + gn] = __float2bfloat16(acc[fm][fn][j] * inv);
      }
    }
  }
}

// ---------------- split-K reduce: dst[i] += p1[i] + p2[i] + p3[i] --------------
__global__ __launch_bounds__(256) void reduce3_kernel(bf16* __restrict__ dst,
    const bf16* __restrict__ p1, const bf16* __restrict__ p2,
    const bf16* __restrict__ p3) {
  int i = (blockIdx.x * 256 + threadIdx.x) * 8;
  bf16x8 a  = *reinterpret_cast<const bf16x8*>(dst + i);
  bf16x8 v1 = *reinterpret_cast<const bf16x8*>(p1 + i);
  bf16x8 v2 = *reinterpret_cast<const bf16x8*>(p2 + i);
  bf16x8 v3 = *reinterpret_cast<const bf16x8*>(p3 + i);
  bf16x8 r;
  #pragma unroll
  for (int j = 0; j < 8; j++)
    r[j] = f2bfb(bfb2f(a[j]) + bfb2f(v1[j]) + bfb2f(v2[j]) + bfb2f(v3[j]));
  *reinterpret_cast<bf16x8*>(dst + i) = r;
}

extern "C" void kernel_launch(void* const* d_in, const int* in_sizes, int n_in,
                              void* d_out, int out_size, void* d_ws, size_t ws_size,
                              hipStream_t stream) {
  const float* x     = (const float*)d_in[0];
  const float* gamma = (const float*)d_in[1];
  const float* beta  = (const float*)d_in[2];
  const float* wq    = (const float*)d_in[3];
  const float* bq    = (const float*)d_in[4];
  const float* wk    = (const float*)d_in[5];
  const float* bk    = (const float*)d_in[6];
  const float* wv    = (const float*)d_in[7];
  const float* bv    = (const float*)d_in[8];
  const float* wp    = (const float*)d_in[9];
  const float* bp    = (const float*)d_in[10];
  float* out = (float*)d_out;

  char* w = (char*)d_ws;
  size_t off = 0;
  float* pstats = (float*)(w + off);   off += 4096;                        // [512][2]
  float* bqk    = (float*)(w + off);   off += 4096;
  float* rspart = (float*)(w + off);   off += (size_t)2 * 4096 * 64 * 4;   // [2][4096][64]
  bf16* wqkb = (bf16*)(w + off);       off += (size_t)1024 * 512 * 2;      // [wq;wk] then wv, wp
  bf16* wvb  = (bf16*)(w + off);       off += (size_t)512 * 512 * 2;
  bf16* wpb  = (bf16*)(w + off);       off += (size_t)512 * 512 * 2;
  bf16* h    = (bf16*)(w + off);       off += (size_t)2 * NPX * CCH * 2;   // 2 slots
  bf16* qk   = (bf16*)(w + off);       off += (size_t)2 * NPX * 1024 * 2;  // 4 slots
  bf16* v    = (bf16*)(w + off);       off += (size_t)2 * NPX * CCH * 2;
  bf16* o    = (bf16*)(w + off);       off += (size_t)2 * NPX * CCH * 2;
  bf16* S    = (bf16*)(w + off);
  size_t need_big = off + (size_t)2 * NPX * NPX * 2;
  const bool big = ws_size >= need_big;

  const long long sBN = (long long)NPX * CCH;      // 4096*512
  const long long sQK = (long long)NPX * 1024;     // 4096*1024
  const long long sS  = (long long)NPX * NPX;      // 4096*4096
  const float scale = 0.04419417382415922f;        // 512^-0.5

  prep_kernel<<<1536, 256, 0, stream>>>(wq, wk, wv, wp, bq, bk, x, wqkb, bqk, pstats);
  gn_apply_kernel<<<dim3(8, 64, 2), 256, 0, stream>>>(x, pstats, gamma, beta, h);

  // fused launch: qkv-proj (512 blocks) + v-proj (256 blocks)
  GemmP pqkv = {h, wqkb, qk, nullptr, bqk, nullptr, nullptr,
                1.f, 512, 512, 512, 1024, sBN, 0, sQK, 0, 32, 8, 1};
  GemmP pv   = {wvb, h, v, bv, nullptr, nullptr, nullptr,
                1.f, 512, 512, 512, 4096, 0, sBN, sBN, 0, 4, 32, 1};
  gemm_any_kernel<<<768, 256, 0, stream>>>(pqkv, pv, 512);

  if (big) {
    // P[b][i][j] = exp(scale * q_i . k_j), partial rowsums stored (both batches)
    GemmP ps = {qk, qk + 512, S, nullptr, nullptr, nullptr, rspart,
                scale, 512, 1024, 1024, 4096, sQK, sQK, sS, 0, 32, 32, 2};
    gemm_any_kernel<<<2048, 256, 0, stream>>>(ps, ps, 2048);
    // PV split-K=4 (rowsum summed in-block); slot 0 of each batch goes to o
    Ptr8 slots{{o, h, qk, qk + sBN, o + sBN, h + sBN, qk + 2 * sBN, qk + 3 * sBN}};
    pv_split_kernel<<<dim3(32, 4, 8), 256, 0, stream>>>(S, v, rspart, sS, sBN, slots, 0);
    reduce3_kernel<<<1024, 256, 0, stream>>>(o, h, qk, qk + sBN);
    reduce3_kernel<<<1024, 256, 0, stream>>>(o + sBN, h + sBN, qk + 2 * sBN, qk + 3 * sBN);
  } else {
    for (int b = 0; b < 2; b++) {
      GemmP ps = {qk + b * sQK, qk + b * sQK + 512, S, nullptr, nullptr, nullptr,
                  rspart + ((size_t)b << 18),
                  scale, 512, 1024, 1024, 4096, 0, 0, 0, 0, 32, 32, 2};
      gemm_any_kernel<<<1024, 256, 0, stream>>>(ps, ps, 1024);
      // partials: o_b (direct), h, h+sBN, d_out-scratch (bf16 view, written pre-out-proj)
      Ptr8 slots{{o + b * sBN, h, h + sBN, (bf16*)out, nullptr, nullptr, nullptr, nullptr}};
      pv_split_kernel<<<dim3(32, 4, 4), 256, 0, stream>>>(S, v + b * sBN,
          rspart + ((size_t)b << 18), 0, 0, slots, 1);
      reduce3_kernel<<<1024, 256, 0, stream>>>(o + b * sBN, h, h + sBN, (bf16*)out);
    }
  }

  // out[c][n] = wp[c][:] @ o[n][:] + bp[c] + x       (M=512, N=4096, K=512)
  GemmP po = {wpb, o, out, bp, nullptr, x, nullptr,
              1.f, 512, 512, 512, 4096, 0, sBN, sBN, sBN, 4, 32, 0};
  gemm_any_kernel<<<256, 256, 0, stream>>>(po, po, 256);
}

// Round 8
// 254.773 us; speedup vs baseline: 1.5940x; 1.0545x over previous
//
#include <hip/hip_runtime.h>
#include <hip/hip_bf16.h>

using bf16 = __hip_bfloat16;
typedef __attribute__((ext_vector_type(4))) float f32x4;
typedef __attribute__((ext_vector_type(8))) short bf16x8;

#define NPX 4096
#define CCH 512

struct Ptr8 { void* p[8]; };

struct GemmP {
  const bf16* A; const bf16* B; void* C;
  const float* bias_m; const float* bias_n; const float* resid;
  float* rspart;
  float alpha; int K;
  int lda, ldb, ldc;
  long long sA, sB, sC, sR;
  int gx, gy;
  int omode;
};

__device__ __forceinline__ void async16(const bf16* g, bf16* l) {
  __builtin_amdgcn_global_load_lds((const __attribute__((address_space(1))) void*)g,
                                   (__attribute__((address_space(3))) void*)l, 16, 0, 0);
}

__device__ __forceinline__ float bfb2f(short s) {
  unsigned u = ((unsigned)(unsigned short)s) << 16;
  float f;
  __builtin_memcpy(&f, &u, 4);
  return f;
}

__device__ __forceinline__ short f2bfb(float f) {
  bf16 h = __float2bfloat16(f);
  short s;
  __builtin_memcpy(&s, &h, 2);
  return s;
}

// ---------------- prep: weight convert + bias pack + GN partial sums ----------
__global__ __launch_bounds__(256) void prep_kernel(
    const float* __restrict__ wq, const float* __restrict__ wk,
    const float* __restrict__ wv, const float* __restrict__ wp,
    const float* __restrict__ bq, const float* __restrict__ bk,
    const float* __restrict__ x,
    bf16* __restrict__ wout, float* __restrict__ bqk, float* __restrict__ pstats) {
  int bid = blockIdx.x;
  int t = threadIdx.x;
  if (bid < 1024) {
    int tid = bid * 256 + t;
    int i = tid * 4;
    int seg = i >> 18;
    const float* in = seg == 0 ? wq : seg == 1 ? wk : seg == 2 ? wv : wp;
    float4 v = *reinterpret_cast<const float4*>(in + (i & 262143));
    wout[i]     = __float2bfloat16(v.x);
    wout[i + 1] = __float2bfloat16(v.y);
    wout[i + 2] = __float2bfloat16(v.z);
    wout[i + 3] = __float2bfloat16(v.w);
    if (tid < 256) {
      int j = tid * 4;
      const float* bsrc = j < 512 ? bq : bk;
      float4 b = *reinterpret_cast<const float4*>(bsrc + (j & 511));
      *reinterpret_cast<float4*>(bqk + j) = b;
    }
  } else {
    int bp = bid - 1024;
    const float* p = x + (size_t)bp * 8192;
    float s = 0.f, s2 = 0.f;
    #pragma unroll
    for (int j = 0; j < 8; j++) {
      float4 v = *reinterpret_cast<const float4*>(p + j * 1024 + t * 4);
      s  += v.x + v.y + v.z + v.w;
      s2 += v.x * v.x + v.y * v.y + v.z * v.z + v.w * v.w;
    }
    #pragma unroll
    for (int off = 32; off >= 1; off >>= 1) {
      s  += __shfl_xor(s, off);
      s2 += __shfl_xor(s2, off);
    }
    __shared__ float ls[8];
    int wv_ = t >> 6;
    if ((t & 63) == 0) { ls[wv_ * 2] = s; ls[wv_ * 2 + 1] = s2; }
    __syncthreads();
    if (t == 0) {
      pstats[bp * 2]     = ls[0] + ls[2] + ls[4] + ls[6];
      pstats[bp * 2 + 1] = ls[1] + ls[3] + ls[5] + ls[7];
    }
  }
}

// ---------------- GroupNorm apply + transpose to [n][c] bf16 -------------------
__global__ __launch_bounds__(256) void gn_apply_kernel(const float* __restrict__ x,
    const float* __restrict__ pstats, const float* __restrict__ gamma,
    const float* __restrict__ beta, bf16* __restrict__ h) {
  __shared__ float tile[64][65];
  __shared__ float mr[4][2];
  int b  = blockIdx.z;
  int c0 = blockIdx.x * 64, n0 = blockIdx.y * 64;
  int t  = threadIdx.x;
  if (t < 4) {
    int g = (c0 >> 4) + t;
    float S = 0.f, S2 = 0.f;
    #pragma unroll
    for (int k2 = 0; k2 < 8; k2++) {
      S  += pstats[((b * 32 + g) * 8 + k2) * 2];
      S2 += pstats[((b * 32 + g) * 8 + k2) * 2 + 1];
    }
    float mean = S * (1.f / 65536.f);
    float var  = S2 * (1.f / 65536.f) - mean * mean;
    mr[t][0] = mean;
    mr[t][1] = rsqrtf(var + 1e-6f);
  }
  __syncthreads();
  int cl = t >> 6, nl = t & 63;
  #pragma unroll
  for (int i = 0; i < 16; i++) {
    int c = c0 + cl + i * 4;
    float v = x[((size_t)b * CCH + c) * NPX + n0 + nl];
    int gi = (cl + i * 4) >> 4;
    tile[cl + i * 4][nl] = (v - mr[gi][0]) * mr[gi][1] * gamma[c] + beta[c];
  }
  __syncthreads();
  #pragma unroll
  for (int i = 0; i < 16; i++) {
    int n = cl + i * 4;
    int c = nl;
    h[((size_t)b * NPX + n0 + n) * CCH + c0 + c] = __float2bfloat16(tile[c][n]);
  }
}

// ---------------- generic B^T GEMM, 1-D grid, dual param blocks ----------------
__global__ __launch_bounds__(256, 4) void gemm_any_kernel(GemmP p0, GemmP p1, unsigned nb0) {
  unsigned nwg = gridDim.x;
  unsigned flat = blockIdx.x;
  unsigned swz = (flat & 7) * (nwg >> 3) + (flat >> 3);
  GemmP p = swz < nb0 ? p0 : p1;
  unsigned local = swz < nb0 ? swz : swz - nb0;
  unsigned bxi = local % p.gx;
  unsigned tmp = local / p.gx;
  unsigned byi = tmp % p.gy;
  unsigned bz  = tmp / p.gy;

  const bf16* A = p.A + (size_t)bz * p.sA;
  const bf16* B = p.B + (size_t)bz * p.sB;
  const int m0 = bxi * 128, n0 = byi * 128;

  __shared__ bf16 ldsA[128 * 64];
  __shared__ bf16 ldsB[128 * 64];

  const int t = threadIdx.x;
  const int lane = t & 63, wv = t >> 6;
  const int wr = (wv >> 1) * 64, wc = (wv & 1) * 64;

  const int r0 = t >> 3;
  const int cb = ((t & 7) << 4) ^ ((r0 & 7) << 4);
  const bf16* gA = A + (size_t)(m0 + r0) * p.lda + (cb >> 1);
  const bf16* gB = B + (size_t)(n0 + r0) * p.ldb + (cb >> 1);
  bf16* lA = ldsA + t * 8;
  bf16* lB = ldsB + t * 8;

  const int arow = wr + (lane & 15);
  const int brow = wc + (lane & 15);
  const int kb   = (lane >> 4) * 16;

  f32x4 acc[4][4] = {};

  for (int k0 = 0; k0 < p.K; k0 += 64) {
    #pragma unroll
    for (int i = 0; i < 4; i++) {
      async16(gA + (size_t)i * 32 * p.lda + k0, lA + i * 2048);
      async16(gB + (size_t)i * 32 * p.ldb + k0, lB + i * 2048);
    }
    __syncthreads();
    #pragma unroll
    for (int ks = 0; ks < 2; ks++) {
      bf16x8 af[4], bfr[4];
      #pragma unroll
      for (int f = 0; f < 4; f++) {
        int ra = arow + f * 16;
        af[f] = *reinterpret_cast<const bf16x8*>(
            reinterpret_cast<const char*>(ldsA) + ra * 128 + ((ks * 64 + kb) ^ ((ra & 7) << 4)));
        int rb = brow + f * 16;
        bfr[f] = *reinterpret_cast<const bf16x8*>(
            reinterpret_cast<const char*>(ldsB) + rb * 128 + ((ks * 64 + kb) ^ ((rb & 7) << 4)));
      }
      #pragma unroll
      for (int fm = 0; fm < 4; fm++)
        #pragma unroll
        for (int fn = 0; fn < 4; fn++)
          acc[fm][fn] = __builtin_amdgcn_mfma_f32_16x16x32_bf16(af[fm], bfr[fn], acc[fm][fn], 0, 0, 0);
    }
    __syncthreads();
  }

  #pragma unroll
  for (int fm = 0; fm < 4; fm++) {
    #pragma unroll
    for (int j = 0; j < 4; j++) {
      int gm = m0 + wr + fm * 16 + (lane >> 4) * 4 + j;
      if (p.omode == 2) {
        float rsum = 0.f;
        #pragma unroll
        for (int fn = 0; fn < 4; fn++) {
          int gn = n0 + wc + fn * 16 + (lane & 15);
          float e = __expf(acc[fm][fn][j] * p.alpha);
          rsum += e;
          reinterpret_cast<bf16*>(p.C)[(size_t)bz * p.sC + (size_t)gm * p.ldc + gn] = __float2bfloat16(e);
        }
        rsum += __shfl_xor(rsum, 1);
        rsum += __shfl_xor(rsum, 2);
        rsum += __shfl_xor(rsum, 4);
        rsum += __shfl_xor(rsum, 8);
        if ((lane & 15) == 0)
          p.rspart[(((size_t)bz * 4096 + gm) << 6) + byi * 2 + (wv & 1)] = rsum;
      } else {
        float bm = p.bias_m ? p.bias_m[gm] : 0.f;
        #pragma unroll
        for (int fn = 0; fn < 4; fn++) {
          int gn = n0 + wc + fn * 16 + (lane & 15);
          float vv = acc[fm][fn][j] * p.alpha + bm;
          if (p.bias_n) vv += p.bias_n[gn];
          if (p.resid)  vv += p.resid[(size_t)bz * p.sR + (size_t)gm * p.ldc + gn];
          if (p.omode == 1)
            reinterpret_cast<bf16*>(p.C)[(size_t)bz * p.sC + (size_t)gm * p.ldc + gn] = __float2bfloat16(vv);
          else
            reinterpret_cast<float*>(p.C)[(size_t)bz * p.sC + (size_t)gm * p.ldc + gn] = vv;
        }
      }
    }
  }
}

// =================== 8-phase 256x256 PV kernel (split-K=4) =====================
// C_partial[i][c] = (1/rowsum[i]) * sum_{j in split} P[i][j] v[c][j]
// 512 threads = 8 waves (2M x 4N); per-wave 128x64 out; BK=64, 2 K-tiles/iter.
#define BAR() __builtin_amdgcn_s_barrier()
#define LGKM0() do { asm volatile("s_waitcnt lgkmcnt(0)" ::: "memory"); \
                     __builtin_amdgcn_sched_barrier(0); } while (0)
#define VMC2() do { asm volatile("s_waitcnt vmcnt(2)" ::: "memory"); \
                    __builtin_amdgcn_sched_barrier(0); } while (0)
#define VMC0() do { asm volatile("s_waitcnt vmcnt(0)" ::: "memory"); \
                    __builtin_amdgcn_sched_barrier(0); } while (0)

#define STG(op, buf, half, kt) do { \
    const bf16* _s = (op ? gB : gA) + (size_t)((half) * 128) * 4096 + (kt) * 64; \
    bf16* _d = &lds[op][buf][half][t * 8]; \
    async16(_s, _d); \
    async16(_s + (size_t)64 * 4096, _d + 4096); \
  } while (0)

#define DSA(buf, mrb) do { \
    _Pragma("unroll") \
    for (int mi = 0; mi < 4; mi++) { \
      int _r = ((mrb) + mi) * 16 + (l & 15); \
      _Pragma("unroll") \
      for (int ks = 0; ks < 2; ks++) \
        aR[mi][ks] = *reinterpret_cast<const bf16x8*>( \
            &lds[0][buf][wm][_r * 64 + ((ks * 32 + (l >> 4) * 8) ^ ((l & 7) << 3))]); \
    } } while (0)

#define DSB(buf, nrb) do { \
    _Pragma("unroll") \
    for (int ni = 0; ni < 2; ni++) { \
      int _r = (wn & 1) * 64 + ((nrb) + ni) * 16 + (l & 15); \
      _Pragma("unroll") \
      for (int ks = 0; ks < 2; ks++) \
        bR[ni][ks] = *reinterpret_cast<const bf16x8*>( \
            &lds[1][buf][wn >> 1][_r * 64 + ((ks * 32 + (l >> 4) * 8) ^ ((l & 7) << 3))]); \
    } } while (0)

#define MMAQ(qm, qn) do { \
    _Pragma("unroll") \
    for (int mi = 0; mi < 4; mi++) \
    _Pragma("unroll") \
    for (int ni = 0; ni < 2; ni++) \
    _Pragma("unroll") \
    for (int ks = 0; ks < 2; ks++) \
      acc[(qm) * 4 + mi][(qn) * 2 + ni] = __builtin_amdgcn_mfma_f32_16x16x32_bf16( \
          aR[mi][ks], bR[ni][ks], acc[(qm) * 4 + mi][(qn) * 2 + ni], 0, 0, 0); \
  } while (0)

#define PH_TAIL(qm, qn) do { \
    BAR(); LGKM0(); \
    __builtin_amdgcn_s_setprio(1); MMAQ(qm, qn); __builtin_amdgcn_s_setprio(0); \
    BAR(); } while (0)

__global__ __launch_bounds__(512, 1) void pv8_kernel(
    const bf16* __restrict__ Sb, const bf16* __restrict__ vb,
    const float* __restrict__ rspart, Ptr8 slots) {
  unsigned nwg = gridDim.x;   // 256
  unsigned flat = blockIdx.x;
  unsigned swz = (flat & 7) * (nwg >> 3) + (flat >> 3);
  const unsigned zz = swz >> 5;          // 0..7: b = zz>>2, s = zz&3
  const unsigned tile = swz & 31;        // 16 m-tiles x 2 n-tiles
  const int m0 = (tile & 15) * 256;
  const int n0 = (tile >> 4) * 256;
  const int b = zz >> 2, s = zz & 3;
  const bf16* A = Sb + (size_t)b * 16777216 + s * 1024;   // lda = 4096
  const bf16* B = vb + (size_t)b * 2097152 + s * 1024;    // ldb = 4096
  bf16* Cp = (bf16*)(slots.p[zz]);

  __shared__ bf16 lds[2][2][2][8192];  // [op A/B][buf][half][128 rows x 64 k]
  __shared__ float rs_lds[256];

  const int t = threadIdx.x;
  const int l = t & 63;
  const int wid = t >> 6;
  const int wm = wid >> 2;      // 0..1
  const int wn = wid & 3;       // 0..3

  // per-thread staging source bases (pre-swizzled column)
  const int swzc = (((t & 7) ^ ((t >> 3) & 7)) << 3);
  const bf16* gA = A + (size_t)(m0 + (t >> 3)) * 4096 + swzc;
  const bf16* gB = B + (size_t)(n0 + (t >> 3)) * 4096 + swzc;

  f32x4 acc[8][4] = {};
  bf16x8 aR[4][2], bR[2][2];

  // ---- prologue: stage A0,A1,B0,B1 of kt0 and B0 of kt1; drain; barrier ----
  STG(0, 0, 0, 0);
  STG(0, 0, 1, 0);
  STG(1, 0, 0, 0);
  STG(1, 0, 1, 0);
  STG(1, 1, 0, 1);
  VMC0();
  BAR();

  // ---- 7 full iterations (kt pairs (0,1)..(12,13)), stages per derived schedule
  #pragma unroll 1
  for (int j = 0; j < 7; j++) {
    const int kt1 = 2 * j + 1, kt2 = 2 * j + 2, kt3 = 2 * j + 3;
    DSA(0, 0); DSB(0, 0); STG(1, 1, 1, kt1); PH_TAIL(0, 0);   // ph0
    DSA(0, 4);            STG(0, 1, 0, kt1); PH_TAIL(1, 0);   // ph1
    DSB(0, 2);            STG(0, 1, 1, kt1); PH_TAIL(1, 1);   // ph2
    DSA(0, 0);            STG(1, 0, 0, kt2); VMC2(); PH_TAIL(0, 1);   // ph3
    DSA(1, 0); DSB(1, 0); STG(1, 0, 1, kt2); PH_TAIL(0, 0);   // ph4
    DSA(1, 4);            STG(0, 0, 0, kt2); PH_TAIL(1, 0);   // ph5
    DSB(1, 2);            STG(0, 0, 1, kt2); PH_TAIL(1, 1);   // ph6
    DSA(1, 0);            STG(1, 1, 0, kt3); VMC2(); PH_TAIL(0, 1);   // ph7
  }
  // ---- last iteration (kt pair (14,15)) — stage only this pair's odd halves
  {
    const int kt1 = 15;
    DSA(0, 0); DSB(0, 0); STG(1, 1, 1, kt1); PH_TAIL(0, 0);
    DSA(0, 4);            STG(0, 1, 0, kt1); PH_TAIL(1, 0);
    DSB(0, 2);            STG(0, 1, 1, kt1); PH_TAIL(1, 1);
    DSA(0, 0);            VMC0(); PH_TAIL(0, 1);
    DSA(1, 0); DSB(1, 0); PH_TAIL(0, 0);
    DSA(1, 4);            PH_TAIL(1, 0);
    DSB(1, 2);            PH_TAIL(1, 1);
    DSA(1, 0);            PH_TAIL(0, 1);
  }

  // ---- epilogue: rowsum (64 partials per row), then normalized C-write ----
  if (t < 256) {
    const float4* pp = reinterpret_cast<const float4*>(
        rspart + (((size_t)b * 4096 + m0 + t) << 6));
    float ssum = 0.f;
    #pragma unroll
    for (int i2 = 0; i2 < 16; i2++) {
      float4 vv = pp[i2];
      ssum += vv.x + vv.y + vv.z + vv.w;
    }
    rs_lds[t] = 1.0f / ssum;
  }
  __syncthreads();

  #pragma unroll
  for (int mr = 0; mr < 8; mr++) {
    #pragma unroll
    for (int jj = 0; jj < 4; jj++) {
      int lrow = wm * 128 + mr * 16 + (l >> 4) * 4 + jj;
      float inv = rs_lds[lrow];
      int gm = m0 + lrow;
      #pragma unroll
      for (int nr = 0; nr < 4; nr++) {
        int gn = n0 + wn * 64 + nr * 16 + (l & 15);
        Cp[(size_t)gm * 512 + gn] = __float2bfloat16(acc[mr][nr][jj] * inv);
      }
    }
  }
}

// ---------------- PV split-K fallback (small-ws path), 128^2 structure ---------
__global__ __launch_bounds__(256, 4) void pv_split_kernel(
    const bf16* __restrict__ Sb, const bf16* __restrict__ vb,
    const float* __restrict__ rspart,
    long long sS, long long sV, Ptr8 slots, int mode) {
  unsigned nx = gridDim.x, ny = gridDim.y;
  unsigned flat = (blockIdx.z * ny + blockIdx.y) * nx + blockIdx.x;
  unsigned nwg = nx * ny * gridDim.z;
  unsigned swz = (flat & 7) * (nwg >> 3) + (flat >> 3);
  unsigned bxi = swz % nx;
  unsigned tmp = swz / nx;
  unsigned byi = tmp % ny;
  unsigned bz  = tmp / ny;

  const int z = bz;
  const int b = mode ? 0 : (z >> 2);
  const int s = mode ? z : (z & 3);
  const bf16* A = Sb + (size_t)b * sS + s * 1024;
  const bf16* B = vb + (size_t)b * sV + s * 1024;
  bf16* Cp = (bf16*)(slots.p[z]);
  const int m0 = bxi * 128, n0 = byi * 128;

  __shared__ bf16 ldsA[128 * 64];
  __shared__ bf16 ldsB[128 * 64];
  __shared__ float rs_lds[128];

  const int t = threadIdx.x;

  if (t < 128) {
    const float4* pp = reinterpret_cast<const float4*>(rspart + (((size_t)b * 4096 + m0 + t) << 6));
    float ssum = 0.f;
    #pragma unroll
    for (int i2 = 0; i2 < 16; i2++) {
      float4 vv = pp[i2];
      ssum += vv.x + vv.y + vv.z + vv.w;
    }
    rs_lds[t] = 1.0f / ssum;
  }

  const int lane = t & 63, wv = t >> 6;
  const int wr = (wv >> 1) * 64, wc = (wv & 1) * 64;

  const int r0 = t >> 3;
  const int cb = ((t & 7) << 4) ^ ((r0 & 7) << 4);
  const bf16* gA = A + (size_t)(m0 + r0) * 4096 + (cb >> 1);
  const bf16* gB = B + (size_t)(n0 + r0) * 4096 + (cb >> 1);
  bf16* lA = ldsA + t * 8;
  bf16* lB = ldsB + t * 8;

  const int arow = wr + (lane & 15);
  const int brow = wc + (lane & 15);
  const int kb   = (lane >> 4) * 16;

  f32x4 acc[4][4] = {};

  for (int k0 = 0; k0 < 1024; k0 += 64) {
    #pragma unroll
    for (int i = 0; i < 4; i++) {
      async16(gA + (size_t)i * 32 * 4096 + k0, lA + i * 2048);
      async16(gB + (size_t)i * 32 * 4096 + k0, lB + i * 2048);
    }
    __syncthreads();
    #pragma unroll
    for (int ks = 0; ks < 2; ks++) {
      bf16x8 af[4], bfr[4];
      #pragma unroll
      for (int f = 0; f < 4; f++) {
        int ra = arow + f * 16;
        af[f] = *reinterpret_cast<const bf16x8*>(
            reinterpret_cast<const char*>(ldsA) + ra * 128 + ((ks * 64 + kb) ^ ((ra & 7) << 4)));
        int rb = brow + f * 16;
        bfr[f] = *reinterpret_cast<const bf16x8*>(
            reinterpret_cast<const char*>(ldsB) + rb * 128 + ((ks * 64 + kb) ^ ((rb & 7) << 4)));
      }
      #pragma unroll
      for (int fm = 0; fm < 4; fm++)
        #pragma unroll
        for (int fn = 0; fn < 4; fn++)
          acc[fm][fn] = __builtin_amdgcn_mfma_f32_16x16x32_bf16(af[fm], bfr[fn], acc[fm][fn], 0, 0, 0);
    }
    __syncthreads();
  }

  #pragma unroll
  for (int fm = 0; fm < 4; fm++) {
    #pragma unroll
    for (int j = 0; j < 4; j++) {
      int lrow = wr + fm * 16 + (lane >> 4) * 4 + j;
      float inv = rs_lds[lrow];
      int gm = m0 + lrow;
      #pragma unroll
      for (int fn = 0; fn < 4; fn++) {
        int gn = n0 + wc + fn * 16 + (lane & 15);
        Cp[(size_t)gm * 512 + gn] = __float2bfloat16(acc[fm][fn][j] * inv);
      }
    }
  }
}

// ---------------- merged split-K reduce (both batches, one launch) -------------
__global__ __launch_bounds__(256) void reduce3x2_kernel(bf16* __restrict__ o,
    const bf16* __restrict__ h, const bf16* __restrict__ qk) {
  int i = (blockIdx.x * 256 + threadIdx.x) * 8;   // [0, 4M)
  int b = i >> 21;                                 // 0 or 1
  int ii = i & 2097151;
  bf16* dst = o + (size_t)b * 2097152 + ii;
  const bf16* p1 = h + (size_t)b * 2097152 + ii;
  const bf16* p2 = qk + (size_t)b * 2 * 2097152 + ii;
  const bf16* p3 = qk + (size_t)(b * 2 + 1) * 2097152 + ii;
  bf16x8 a  = *reinterpret_cast<const bf16x8*>(dst);
  bf16x8 v1 = *reinterpret_cast<const bf16x8*>(p1);
  bf16x8 v2 = *reinterpret_cast<const bf16x8*>(p2);
  bf16x8 v3 = *reinterpret_cast<const bf16x8*>(p3);
  bf16x8 r;
  #pragma unroll
  for (int j = 0; j < 8; j++)
    r[j] = f2bfb(bfb2f(a[j]) + bfb2f(v1[j]) + bfb2f(v2[j]) + bfb2f(v3[j]));
  *reinterpret_cast<bf16x8*>(dst) = r;
}

// ---------------- fallback reduce --------------------------------------------
__global__ __launch_bounds__(256) void reduce3_kernel(bf16* __restrict__ dst,
    const bf16* __restrict__ p1, const bf16* __restrict__ p2,
    const bf16* __restrict__ p3) {
  int i = (blockIdx.x * 256 + threadIdx.x) * 8;
  bf16x8 a  = *reinterpret_cast<const bf16x8*>(dst + i);
  bf16x8 v1 = *reinterpret_cast<const bf16x8*>(p1 + i);
  bf16x8 v2 = *reinterpret_cast<const bf16x8*>(p2 + i);
  bf16x8 v3 = *reinterpret_cast<const bf16x8*>(p3 + i);
  bf16x8 r;
  #pragma unroll
  for (int j = 0; j < 8; j++)
    r[j] = f2bfb(bfb2f(a[j]) + bfb2f(v1[j]) + bfb2f(v2[j]) + bfb2f(v3[j]));
  *reinterpret_cast<bf16x8*>(dst + i) = r;
}

extern "C" void kernel_launch(void* const* d_in, const int* in_sizes, int n_in,
                              void* d_out, int out_size, void* d_ws, size_t ws_size,
                              hipStream_t stream) {
  const float* x     = (const float*)d_in[0];
  const float* gamma = (const float*)d_in[1];
  const float* beta  = (const float*)d_in[2];
  const float* wq    = (const float*)d_in[3];
  const float* bq    = (const float*)d_in[4];
  const float* wk    = (const float*)d_in[5];
  const float* bk    = (const float*)d_in[6];
  const float* wv    = (const float*)d_in[7];
  const float* bv    = (const float*)d_in[8];
  const float* wp    = (const float*)d_in[9];
  const float* bp    = (const float*)d_in[10];
  float* out = (float*)d_out;

  char* w = (char*)d_ws;
  size_t off = 0;
  float* pstats = (float*)(w + off);   off += 4096;
  float* bqk    = (float*)(w + off);   off += 4096;
  float* rspart = (float*)(w + off);   off += (size_t)2 * 4096 * 64 * 4;
  bf16* wqkb = (bf16*)(w + off);       off += (size_t)1024 * 512 * 2;
  bf16* wvb  = (bf16*)(w + off);       off += (size_t)512 * 512 * 2;
  bf16* wpb  = (bf16*)(w + off);       off += (size_t)512 * 512 * 2;
  bf16* h    = (bf16*)(w + off);       off += (size_t)2 * NPX * CCH * 2;
  bf16* qk   = (bf16*)(w + off);       off += (size_t)2 * NPX * 1024 * 2;
  bf16* v    = (bf16*)(w + off);       off += (size_t)2 * NPX * CCH * 2;
  bf16* o    = (bf16*)(w + off);       off += (size_t)2 * NPX * CCH * 2;
  bf16* S    = (bf16*)(w + off);
  size_t need_big = off + (size_t)2 * NPX * NPX * 2;
  const bool big = ws_size >= need_big;

  const long long sBN = (long long)NPX * CCH;
  const long long sQK = (long long)NPX * 1024;
  const long long sS  = (long long)NPX * NPX;
  const float scale = 0.04419417382415922f;

  prep_kernel<<<1536, 256, 0, stream>>>(wq, wk, wv, wp, bq, bk, x, wqkb, bqk, pstats);
  gn_apply_kernel<<<dim3(8, 64, 2), 256, 0, stream>>>(x, pstats, gamma, beta, h);

  GemmP pqkv = {h, wqkb, qk, nullptr, bqk, nullptr, nullptr,
                1.f, 512, 512, 512, 1024, sBN, 0, sQK, 0, 32, 8, 1};
  GemmP pv   = {wvb, h, v, bv, nullptr, nullptr, nullptr,
                1.f, 512, 512, 512, 4096, 0, sBN, sBN, 0, 4, 32, 1};
  gemm_any_kernel<<<768, 256, 0, stream>>>(pqkv, pv, 512);

  if (big) {
    GemmP ps = {qk, qk + 512, S, nullptr, nullptr, nullptr, rspart,
                scale, 512, 1024, 1024, 4096, sQK, sQK, sS, 0, 32, 32, 2};
    gemm_any_kernel<<<2048, 256, 0, stream>>>(ps, ps, 2048);
    Ptr8 slots{{o, h, qk, qk + sBN, o + sBN, h + sBN, qk + 2 * sBN, qk + 3 * sBN}};
    pv8_kernel<<<256, 512, 0, stream>>>(S, v, rspart, slots);
    reduce3x2_kernel<<<2048, 256, 0, stream>>>(o, h, qk);
  } else {
    for (int b = 0; b < 2; b++) {
      GemmP ps = {qk + b * sQK, qk + b * sQK + 512, S, nullptr, nullptr, nullptr,
                  rspart + ((size_t)b << 18),
                  scale, 512, 1024, 1024, 4096, 0, 0, 0, 0, 32, 32, 2};
      gemm_any_kernel<<<1024, 256, 0, stream>>>(ps, ps, 1024);
      Ptr8 slots{{o + b * sBN, h, h + sBN, (bf16*)out, nullptr, nullptr, nullptr, nullptr}};
      pv_split_kernel<<<dim3(32, 4, 4), 256, 0, stream>>>(S, v + b * sBN,
          rspart + ((size_t)b << 18), 0, 0, slots, 1);
      reduce3_kernel<<<1024, 256, 0, stream>>>(o + b * sBN, h, h + sBN, (bf16*)out);
    }
  }

  GemmP po = {wpb, o, out, bp, nullptr, x, nullptr,
              1.f, 512, 512, 512, 4096, 0, sBN, sBN, sBN, 4, 32, 0};
  gemm_any_kernel<<<256, 256, 0, stream>>>(po, po, 256);
}

// Round 10
// 248.871 us; speedup vs baseline: 1.6318x; 1.0237x over previous
//
#include <hip/hip_runtime.h>
#include <hip/hip_bf16.h>

using bf16 = __hip_bfloat16;
typedef __attribute__((ext_vector_type(4))) float f32x4;
typedef __attribute__((ext_vector_type(8))) short bf16x8;

#define NPX 4096
#define CCH 512

struct Ptr8 { void* p[8]; };

struct GemmP {
  const bf16* A; const bf16* B; void* C;
  const float* bias_m; const float* bias_n; const float* resid;
  float* rspart;
  float alpha; int K;
  int lda, ldb, ldc;
  long long sA, sB, sC, sR;
  int gx, gy;
  int omode;
};

__device__ __forceinline__ void async16(const bf16* g, bf16* l) {
  __builtin_amdgcn_global_load_lds((const __attribute__((address_space(1))) void*)g,
                                   (__attribute__((address_space(3))) void*)l, 16, 0, 0);
}

__device__ __forceinline__ float bfb2f(short s) {
  unsigned u = ((unsigned)(unsigned short)s) << 16;
  float f;
  __builtin_memcpy(&f, &u, 4);
  return f;
}

__device__ __forceinline__ short f2bfb(float f) {
  bf16 h = __float2bfloat16(f);
  short s;
  __builtin_memcpy(&s, &h, 2);
  return s;
}

// ---------------- prep: weight convert + bias pack + GN partial sums ----------
__global__ __launch_bounds__(256) void prep_kernel(
    const float* __restrict__ wq, const float* __restrict__ wk,
    const float* __restrict__ wv, const float* __restrict__ wp,
    const float* __restrict__ bq, const float* __restrict__ bk,
    const float* __restrict__ x,
    bf16* __restrict__ wout, float* __restrict__ bqk, float* __restrict__ pstats) {
  int bid = blockIdx.x;
  int t = threadIdx.x;
  if (bid < 1024) {
    int tid = bid * 256 + t;
    int i = tid * 4;
    int seg = i >> 18;
    const float* in = seg == 0 ? wq : seg == 1 ? wk : seg == 2 ? wv : wp;
    float4 v = *reinterpret_cast<const float4*>(in + (i & 262143));
    wout[i]     = __float2bfloat16(v.x);
    wout[i + 1] = __float2bfloat16(v.y);
    wout[i + 2] = __float2bfloat16(v.z);
    wout[i + 3] = __float2bfloat16(v.w);
    if (tid < 256) {
      int j = tid * 4;
      const float* bsrc = j < 512 ? bq : bk;
      float4 b = *reinterpret_cast<const float4*>(bsrc + (j & 511));
      *reinterpret_cast<float4*>(bqk + j) = b;
    }
  } else {
    int bp = bid - 1024;
    const float* p = x + (size_t)bp * 8192;
    float s = 0.f, s2 = 0.f;
    #pragma unroll
    for (int j = 0; j < 8; j++) {
      float4 v = *reinterpret_cast<const float4*>(p + j * 1024 + t * 4);
      s  += v.x + v.y + v.z + v.w;
      s2 += v.x * v.x + v.y * v.y + v.z * v.z + v.w * v.w;
    }
    #pragma unroll
    for (int off = 32; off >= 1; off >>= 1) {
      s  += __shfl_xor(s, off);
      s2 += __shfl_xor(s2, off);
    }
    __shared__ float ls[8];
    int wv_ = t >> 6;
    if ((t & 63) == 0) { ls[wv_ * 2] = s; ls[wv_ * 2 + 1] = s2; }
    __syncthreads();
    if (t == 0) {
      pstats[bp * 2]     = ls[0] + ls[2] + ls[4] + ls[6];
      pstats[bp * 2 + 1] = ls[1] + ls[3] + ls[5] + ls[7];
    }
  }
}

// ---------------- GroupNorm apply + transpose to [n][c] bf16 -------------------
__global__ __launch_bounds__(256) void gn_apply_kernel(const float* __restrict__ x,
    const float* __restrict__ pstats, const float* __restrict__ gamma,
    const float* __restrict__ beta, bf16* __restrict__ h) {
  __shared__ float tile[64][65];
  __shared__ float mr[4][2];
  int b  = blockIdx.z;
  int c0 = blockIdx.x * 64, n0 = blockIdx.y * 64;
  int t  = threadIdx.x;
  if (t < 4) {
    int g = (c0 >> 4) + t;
    float S = 0.f, S2 = 0.f;
    #pragma unroll
    for (int k2 = 0; k2 < 8; k2++) {
      S  += pstats[((b * 32 + g) * 8 + k2) * 2];
      S2 += pstats[((b * 32 + g) * 8 + k2) * 2 + 1];
    }
    float mean = S * (1.f / 65536.f);
    float var  = S2 * (1.f / 65536.f) - mean * mean;
    mr[t][0] = mean;
    mr[t][1] = rsqrtf(var + 1e-6f);
  }
  __syncthreads();
  int cl = t >> 6, nl = t & 63;
  #pragma unroll
  for (int i = 0; i < 16; i++) {
    int c = c0 + cl + i * 4;
    float v = x[((size_t)b * CCH + c) * NPX + n0 + nl];
    int gi = (cl + i * 4) >> 4;
    tile[cl + i * 4][nl] = (v - mr[gi][0]) * mr[gi][1] * gamma[c] + beta[c];
  }
  __syncthreads();
  #pragma unroll
  for (int i = 0; i < 16; i++) {
    int n = cl + i * 4;
    int c = nl;
    h[((size_t)b * NPX + n0 + n) * CCH + c0 + c] = __float2bfloat16(tile[c][n]);
  }
}

// ---------------- generic B^T GEMM, 1-D grid, dual param blocks ----------------
__global__ __launch_bounds__(256, 4) void gemm_any_kernel(GemmP p0, GemmP p1, unsigned nb0) {
  unsigned nwg = gridDim.x;
  unsigned flat = blockIdx.x;
  unsigned swz = (flat & 7) * (nwg >> 3) + (flat >> 3);
  GemmP p = swz < nb0 ? p0 : p1;
  unsigned local = swz < nb0 ? swz : swz - nb0;
  unsigned bxi = local % p.gx;
  unsigned tmp = local / p.gx;
  unsigned byi = tmp % p.gy;
  unsigned bz  = tmp / p.gy;

  const bf16* A = p.A + (size_t)bz * p.sA;
  const bf16* B = p.B + (size_t)bz * p.sB;
  const int m0 = bxi * 128, n0 = byi * 128;

  __shared__ bf16 ldsA[128 * 64];
  __shared__ bf16 ldsB[128 * 64];

  const int t = threadIdx.x;
  const int lane = t & 63, wv = t >> 6;
  const int wr = (wv >> 1) * 64, wc = (wv & 1) * 64;

  const int r0 = t >> 3;
  const int cb = ((t & 7) << 4) ^ ((r0 & 7) << 4);
  const bf16* gA = A + (size_t)(m0 + r0) * p.lda + (cb >> 1);
  const bf16* gB = B + (size_t)(n0 + r0) * p.ldb + (cb >> 1);
  bf16* lA = ldsA + t * 8;
  bf16* lB = ldsB + t * 8;

  const int arow = wr + (lane & 15);
  const int brow = wc + (lane & 15);
  const int kb   = (lane >> 4) * 16;

  f32x4 acc[4][4] = {};

  for (int k0 = 0; k0 < p.K; k0 += 64) {
    #pragma unroll
    for (int i = 0; i < 4; i++) {
      async16(gA + (size_t)i * 32 * p.lda + k0, lA + i * 2048);
      async16(gB + (size_t)i * 32 * p.ldb + k0, lB + i * 2048);
    }
    __syncthreads();
    #pragma unroll
    for (int ks = 0; ks < 2; ks++) {
      bf16x8 af[4], bfr[4];
      #pragma unroll
      for (int f = 0; f < 4; f++) {
        int ra = arow + f * 16;
        af[f] = *reinterpret_cast<const bf16x8*>(
            reinterpret_cast<const char*>(ldsA) + ra * 128 + ((ks * 64 + kb) ^ ((ra & 7) << 4)));
        int rb = brow + f * 16;
        bfr[f] = *reinterpret_cast<const bf16x8*>(
            reinterpret_cast<const char*>(ldsB) + rb * 128 + ((ks * 64 + kb) ^ ((rb & 7) << 4)));
      }
      #pragma unroll
      for (int fm = 0; fm < 4; fm++)
        #pragma unroll
        for (int fn = 0; fn < 4; fn++)
          acc[fm][fn] = __builtin_amdgcn_mfma_f32_16x16x32_bf16(af[fm], bfr[fn], acc[fm][fn], 0, 0, 0);
    }
    __syncthreads();
  }

  #pragma unroll
  for (int fm = 0; fm < 4; fm++) {
    #pragma unroll
    for (int j = 0; j < 4; j++) {
      int gm = m0 + wr + fm * 16 + (lane >> 4) * 4 + j;
      if (p.omode == 2) {
        float rsum = 0.f;
        #pragma unroll
        for (int fn = 0; fn < 4; fn++) {
          int gn = n0 + wc + fn * 16 + (lane & 15);
          float e = __expf(acc[fm][fn][j] * p.alpha);
          rsum += e;
          reinterpret_cast<bf16*>(p.C)[(size_t)bz * p.sC + (size_t)gm * p.ldc + gn] = __float2bfloat16(e);
        }
        rsum += __shfl_xor(rsum, 1);
        rsum += __shfl_xor(rsum, 2);
        rsum += __shfl_xor(rsum, 4);
        rsum += __shfl_xor(rsum, 8);
        if ((lane & 15) == 0)
          p.rspart[(((size_t)bz * 4096 + gm) << 6) + byi * 2 + (wv & 1)] = rsum;
      } else {
        float bm = p.bias_m ? p.bias_m[gm] : 0.f;
        #pragma unroll
        for (int fn = 0; fn < 4; fn++) {
          int gn = n0 + wc + fn * 16 + (lane & 15);
          float vv = acc[fm][fn][j] * p.alpha + bm;
          if (p.bias_n) vv += p.bias_n[gn];
          if (p.resid)  vv += p.resid[(size_t)bz * p.sR + (size_t)gm * p.ldc + gn];
          if (p.omode == 1)
            reinterpret_cast<bf16*>(p.C)[(size_t)bz * p.sC + (size_t)gm * p.ldc + gn] = __float2bfloat16(vv);
          else
            reinterpret_cast<float*>(p.C)[(size_t)bz * p.sC + (size_t)gm * p.ldc + gn] = vv;
        }
      }
    }
  }
}

// =================== shared 8-phase 256x256 machinery ==========================
#define BAR() __builtin_amdgcn_s_barrier()
#define LGKM0() do { asm volatile("s_waitcnt lgkmcnt(0)" ::: "memory"); \
                     __builtin_amdgcn_sched_barrier(0); } while (0)
#define VMC2() do { asm volatile("s_waitcnt vmcnt(2)" ::: "memory"); \
                    __builtin_amdgcn_sched_barrier(0); } while (0)
#define VMC0() do { asm volatile("s_waitcnt vmcnt(0)" ::: "memory"); \
                    __builtin_amdgcn_sched_barrier(0); } while (0)

#define STG(op, buf, half, kt, LD) do { \
    const bf16* _s = (op ? gB : gA) + (size_t)((half) * 128) * (LD) + (kt) * 64; \
    bf16* _d = &lds[op][buf][half][t * 8]; \
    async16(_s, _d); \
    async16(_s + (size_t)64 * (LD), _d + 4096); \
  } while (0)

#define DSA(buf, mrb) do { \
    _Pragma("unroll") \
    for (int mi = 0; mi < 4; mi++) { \
      int _r = ((mrb) + mi) * 16 + (l & 15); \
      _Pragma("unroll") \
      for (int ks = 0; ks < 2; ks++) \
        aR[mi][ks] = *reinterpret_cast<const bf16x8*>( \
            &lds[0][buf][wm][_r * 64 + ((ks * 32 + (l >> 4) * 8) ^ ((l & 7) << 3))]); \
    } } while (0)

#define DSB(buf, nrb) do { \
    _Pragma("unroll") \
    for (int ni = 0; ni < 2; ni++) { \
      int _r = (wn & 1) * 64 + ((nrb) + ni) * 16 + (l & 15); \
      _Pragma("unroll") \
      for (int ks = 0; ks < 2; ks++) \
        bR[ni][ks] = *reinterpret_cast<const bf16x8*>( \
            &lds[1][buf][wn >> 1][_r * 64 + ((ks * 32 + (l >> 4) * 8) ^ ((l & 7) << 3))]); \
    } } while (0)

#define MMAQ(qm, qn) do { \
    _Pragma("unroll") \
    for (int mi = 0; mi < 4; mi++) \
    _Pragma("unroll") \
    for (int ni = 0; ni < 2; ni++) \
    _Pragma("unroll") \
    for (int ks = 0; ks < 2; ks++) \
      acc[(qm) * 4 + mi][(qn) * 2 + ni] = __builtin_amdgcn_mfma_f32_16x16x32_bf16( \
          aR[mi][ks], bR[ni][ks], acc[(qm) * 4 + mi][(qn) * 2 + ni], 0, 0, 0); \
  } while (0)

#define PH_TAIL(qm, qn) do { \
    BAR(); LGKM0(); \
    __builtin_amdgcn_s_setprio(1); MMAQ(qm, qn); __builtin_amdgcn_s_setprio(0); \
    BAR(); } while (0)

// =================== 8-phase PV kernel (split-K=4) =============================
__global__ __launch_bounds__(512, 1) void pv8_kernel(
    const bf16* __restrict__ Sb, const bf16* __restrict__ vb,
    const float* __restrict__ rspart, Ptr8 slots) {
  unsigned nwg = gridDim.x;   // 256
  unsigned flat = blockIdx.x;
  unsigned swz = (flat & 7) * (nwg >> 3) + (flat >> 3);
  const unsigned zz = swz >> 5;
  const unsigned tile = swz & 31;
  const int m0 = (tile & 15) * 256;
  const int n0 = (tile >> 4) * 256;
  const int b = zz >> 2, s = zz & 3;
  const bf16* A = Sb + (size_t)b * 16777216 + s * 1024;
  const bf16* B = vb + (size_t)b * 2097152 + s * 1024;
  bf16* Cp = (bf16*)(slots.p[zz]);

  __shared__ bf16 lds[2][2][2][8192];
  __shared__ float rs_lds[256];

  const int t = threadIdx.x;
  const int l = t & 63;
  const int wid = t >> 6;
  const int wm = wid >> 2;
  const int wn = wid & 3;

  const int swzc = (((t & 7) ^ ((t >> 3) & 7)) << 3);
  const bf16* gA = A + (size_t)(m0 + (t >> 3)) * 4096 + swzc;
  const bf16* gB = B + (size_t)(n0 + (t >> 3)) * 4096 + swzc;

  f32x4 acc[8][4] = {};
  bf16x8 aR[4][2], bR[2][2];

  STG(0, 0, 0, 0, 4096);
  STG(0, 0, 1, 0, 4096);
  STG(1, 0, 0, 0, 4096);
  STG(1, 0, 1, 0, 4096);
  STG(1, 1, 0, 1, 4096);
  VMC0();
  BAR();

  #pragma unroll 1
  for (int j = 0; j < 7; j++) {
    const int kt1 = 2 * j + 1, kt2 = 2 * j + 2, kt3 = 2 * j + 3;
    DSA(0, 0); DSB(0, 0); STG(1, 1, 1, kt1, 4096); PH_TAIL(0, 0);
    DSA(0, 4);            STG(0, 1, 0, kt1, 4096); PH_TAIL(1, 0);
    DSB(0, 2);            STG(0, 1, 1, kt1, 4096); PH_TAIL(1, 1);
    DSA(0, 0);            STG(1, 0, 0, kt2, 4096); VMC2(); PH_TAIL(0, 1);
    DSA(1, 0); DSB(1, 0); STG(1, 0, 1, kt2, 4096); PH_TAIL(0, 0);
    DSA(1, 4);            STG(0, 0, 0, kt2, 4096); PH_TAIL(1, 0);
    DSB(1, 2);            STG(0, 0, 1, kt2, 4096); PH_TAIL(1, 1);
    DSA(1, 0);            STG(1, 1, 0, kt3, 4096); VMC2(); PH_TAIL(0, 1);
  }
  {
    const int kt1 = 15;
    DSA(0, 0); DSB(0, 0); STG(1, 1, 1, kt1, 4096); PH_TAIL(0, 0);
    DSA(0, 4);            STG(0, 1, 0, kt1, 4096); PH_TAIL(1, 0);
    DSB(0, 2);            STG(0, 1, 1, kt1, 4096); PH_TAIL(1, 1);
    DSA(0, 0);            VMC0(); PH_TAIL(0, 1);
    DSA(1, 0); DSB(1, 0); PH_TAIL(0, 0);
    DSA(1, 4);            PH_TAIL(1, 0);
    DSB(1, 2);            PH_TAIL(1, 1);
    DSA(1, 0);            PH_TAIL(0, 1);
  }

  if (t < 256) {
    const float4* pp = reinterpret_cast<const float4*>(
        rspart + (((size_t)b * 4096 + m0 + t) << 6));
    float ssum = 0.f;
    #pragma unroll
    for (int i2 = 0; i2 < 16; i2++) {
      float4 vv = pp[i2];
      ssum += vv.x + vv.y + vv.z + vv.w;
    }
    rs_lds[t] = 1.0f / ssum;
  }
  __syncthreads();

  #pragma unroll
  for (int mr = 0; mr < 8; mr++) {
    #pragma unroll
    for (int jj = 0; jj < 4; jj++) {
      int lrow = wm * 128 + mr * 16 + (l >> 4) * 4 + jj;
      float inv = rs_lds[lrow];
      int gm = m0 + lrow;
      #pragma unroll
      for (int nr = 0; nr < 4; nr++) {
        int gn = n0 + wn * 64 + nr * 16 + (l & 15);
        Cp[(size_t)gm * 512 + gn] = __float2bfloat16(acc[mr][nr][jj] * inv);
      }
    }
  }
}

// =================== 8-phase QK^T kernel: P = exp(scale*q.k) + rspart ==========
// M=N=4096, K=512 per batch; A = q rows (ld 1024), B = k rows (ld 1024).
__global__ __launch_bounds__(512, 1) void qk8_kernel(
    const bf16* __restrict__ qkb, bf16* __restrict__ Sb,
    float* __restrict__ rspart, float scale) {
  unsigned nwg = gridDim.x;   // 512
  unsigned flat = blockIdx.x;
  unsigned swz = (flat & 7) * (nwg >> 3) + (flat >> 3);
  const unsigned b = swz >> 8;
  const unsigned tile = swz & 255;       // 16 m-tiles x 16 n-tiles
  const int m0 = (tile & 15) * 256;
  const int n0 = (tile >> 4) * 256;
  const bf16* A = qkb + (size_t)b * 4194304;        // q: cols [0,512), ld 1024
  const bf16* B = qkb + (size_t)b * 4194304 + 512;  // k: cols [512,1024)
  bf16* Cp = Sb + (size_t)b * 16777216;

  __shared__ bf16 lds[2][2][2][8192];

  const int t = threadIdx.x;
  const int l = t & 63;
  const int wid = t >> 6;
  const int wm = wid >> 2;
  const int wn = wid & 3;

  const int swzc = (((t & 7) ^ ((t >> 3) & 7)) << 3);
  const bf16* gA = A + (size_t)(m0 + (t >> 3)) * 1024 + swzc;
  const bf16* gB = B + (size_t)(n0 + (t >> 3)) * 1024 + swzc;

  f32x4 acc[8][4] = {};
  bf16x8 aR[4][2], bR[2][2];

  // K=512 -> kt 0..7 (4 pairs): prologue + 3 full iters + tail
  STG(0, 0, 0, 0, 1024);
  STG(0, 0, 1, 0, 1024);
  STG(1, 0, 0, 0, 1024);
  STG(1, 0, 1, 0, 1024);
  STG(1, 1, 0, 1, 1024);
  VMC0();
  BAR();

  #pragma unroll 1
  for (int j = 0; j < 3; j++) {
    const int kt1 = 2 * j + 1, kt2 = 2 * j + 2, kt3 = 2 * j + 3;
    DSA(0, 0); DSB(0, 0); STG(1, 1, 1, kt1, 1024); PH_TAIL(0, 0);
    DSA(0, 4);            STG(0, 1, 0, kt1, 1024); PH_TAIL(1, 0);
    DSB(0, 2);            STG(0, 1, 1, kt1, 1024); PH_TAIL(1, 1);
    DSA(0, 0);            STG(1, 0, 0, kt2, 1024); VMC2(); PH_TAIL(0, 1);
    DSA(1, 0); DSB(1, 0); STG(1, 0, 1, kt2, 1024); PH_TAIL(0, 0);
    DSA(1, 4);            STG(0, 0, 0, kt2, 1024); PH_TAIL(1, 0);
    DSB(1, 2);            STG(0, 0, 1, kt2, 1024); PH_TAIL(1, 1);
    DSA(1, 0);            STG(1, 1, 0, kt3, 1024); VMC2(); PH_TAIL(0, 1);
  }
  {
    const int kt1 = 7;
    DSA(0, 0); DSB(0, 0); STG(1, 1, 1, kt1, 1024); PH_TAIL(0, 0);
    DSA(0, 4);            STG(0, 1, 0, kt1, 1024); PH_TAIL(1, 0);
    DSB(0, 2);            STG(0, 1, 1, kt1, 1024); PH_TAIL(1, 1);
    DSA(0, 0);            VMC0(); PH_TAIL(0, 1);
    DSA(1, 0); DSB(1, 0); PH_TAIL(0, 0);
    DSA(1, 4);            PH_TAIL(1, 0);
    DSB(1, 2);            PH_TAIL(1, 1);
    DSA(1, 0);            PH_TAIL(0, 1);
  }

  // epilogue: e = exp(acc*scale); store bf16 P; per-row partial sums -> rspart
  const int ntile = tile >> 4;   // n-block index 0..15; slot = ntile*4 + wn
  #pragma unroll
  for (int mr = 0; mr < 8; mr++) {
    #pragma unroll
    for (int jj = 0; jj < 4; jj++) {
      int gm = m0 + wm * 128 + mr * 16 + (l >> 4) * 4 + jj;
      float rsum = 0.f;
      #pragma unroll
      for (int nr = 0; nr < 4; nr++) {
        int gn = n0 + wn * 64 + nr * 16 + (l & 15);
        float e = __expf(acc[mr][nr][jj] * scale);
        rsum += e;
        Cp[(size_t)gm * 4096 + gn] = __float2bfloat16(e);
      }
      rsum += __shfl_xor(rsum, 1);
      rsum += __shfl_xor(rsum, 2);
      rsum += __shfl_xor(rsum, 4);
      rsum += __shfl_xor(rsum, 8);
      if ((l & 15) == 0)
        rspart[(((size_t)b * 4096 + gm) << 6) + ntile * 4 + wn] = rsum;
    }
  }
}

// ---------------- PV split-K fallback (small-ws path), 128^2 structure ---------
__global__ __launch_bounds__(256, 4) void pv_split_kernel(
    const bf16* __restrict__ Sb, const bf16* __restrict__ vb,
    const float* __restrict__ rspart,
    long long sS, long long sV, Ptr8 slots, int mode) {
  unsigned nx = gridDim.x, ny = gridDim.y;
  unsigned flat = (blockIdx.z * ny + blockIdx.y) * nx + blockIdx.x;
  unsigned nwg = nx * ny * gridDim.z;
  unsigned swz = (flat & 7) * (nwg >> 3) + (flat >> 3);
  unsigned bxi = swz % nx;
  unsigned tmp = swz / nx;
  unsigned byi = tmp % ny;
  unsigned bz  = tmp / ny;

  const int z = bz;
  const int b = mode ? 0 : (z >> 2);
  const int s = mode ? z : (z & 3);
  const bf16* A = Sb + (size_t)b * sS + s * 1024;
  const bf16* B = vb + (size_t)b * sV + s * 1024;
  bf16* Cp = (bf16*)(slots.p[z]);
  const int m0 = bxi * 128, n0 = byi * 128;

  __shared__ bf16 ldsA[128 * 64];
  __shared__ bf16 ldsB[128 * 64];
  __shared__ float rs_lds[128];

  const int t = threadIdx.x;

  if (t < 128) {
    const float4* pp = reinterpret_cast<const float4*>(rspart + (((size_t)b * 4096 + m0 + t) << 6));
    float ssum = 0.f;
    #pragma unroll
    for (int i2 = 0; i2 < 16; i2++) {
      float4 vv = pp[i2];
      ssum += vv.x + vv.y + vv.z + vv.w;
    }
    rs_lds[t] = 1.0f / ssum;
  }

  const int lane = t & 63, wv = t >> 6;
  const int wr = (wv >> 1) * 64, wc = (wv & 1) * 64;

  const int r0 = t >> 3;
  const int cb = ((t & 7) << 4) ^ ((r0 & 7) << 4);
  const bf16* gA = A + (size_t)(m0 + r0) * 4096 + (cb >> 1);
  const bf16* gB = B + (size_t)(n0 + r0) * 4096 + (cb >> 1);
  bf16* lA = ldsA + t * 8;
  bf16* lB = ldsB + t * 8;

  const int arow = wr + (lane & 15);
  const int brow = wc + (lane & 15);
  const int kb   = (lane >> 4) * 16;

  f32x4 acc[4][4] = {};

  for (int k0 = 0; k0 < 1024; k0 += 64) {
    #pragma unroll
    for (int i = 0; i < 4; i++) {
      async16(gA + (size_t)i * 32 * 4096 + k0, lA + i * 2048);
      async16(gB + (size_t)i * 32 * 4096 + k0, lB + i * 2048);
    }
    __syncthreads();
    #pragma unroll
    for (int ks = 0; ks < 2; ks++) {
      bf16x8 af[4], bfr[4];
      #pragma unroll
      for (int f = 0; f < 4; f++) {
        int ra = arow + f * 16;
        af[f] = *reinterpret_cast<const bf16x8*>(
            reinterpret_cast<const char*>(ldsA) + ra * 128 + ((ks * 64 + kb) ^ ((ra & 7) << 4)));
        int rb = brow + f * 16;
        bfr[f] = *reinterpret_cast<const bf16x8*>(
            reinterpret_cast<const char*>(ldsB) + rb * 128 + ((ks * 64 + kb) ^ ((rb & 7) << 4)));
      }
      #pragma unroll
      for (int fm = 0; fm < 4; fm++)
        #pragma unroll
        for (int fn = 0; fn < 4; fn++)
          acc[fm][fn] = __builtin_amdgcn_mfma_f32_16x16x32_bf16(af[fm], bfr[fn], acc[fm][fn], 0, 0, 0);
    }
    __syncthreads();
  }

  #pragma unroll
  for (int fm = 0; fm < 4; fm++) {
    #pragma unroll
    for (int j = 0; j < 4; j++) {
      int lrow = wr + fm * 16 + (lane >> 4) * 4 + j;
      float inv = rs_lds[lrow];
      int gm = m0 + lrow;
      #pragma unroll
      for (int fn = 0; fn < 4; fn++) {
        int gn = n0 + wc + fn * 16 + (lane & 15);
        Cp[(size_t)gm * 512 + gn] = __float2bfloat16(acc[fm][fn][j] * inv);
      }
    }
  }
}

// ---------------- merged split-K reduce (both batches, one launch) -------------
__global__ __launch_bounds__(256) void reduce3x2_kernel(bf16* __restrict__ o,
    const bf16* __restrict__ h, const bf16* __restrict__ qk) {
  int i = (blockIdx.x * 256 + threadIdx.x) * 8;
  int b = i >> 21;
  int ii = i & 2097151;
  bf16* dst = o + (size_t)b * 2097152 + ii;
  const bf16* p1 = h + (size_t)b * 2097152 + ii;
  const bf16* p2 = qk + (size_t)b * 2 * 2097152 + ii;
  const bf16* p3 = qk + (size_t)(b * 2 + 1) * 2097152 + ii;
  bf16x8 a  = *reinterpret_cast<const bf16x8*>(dst);
  bf16x8 v1 = *reinterpret_cast<const bf16x8*>(p1);
  bf16x8 v2 = *reinterpret_cast<const bf16x8*>(p2);
  bf16x8 v3 = *reinterpret_cast<const bf16x8*>(p3);
  bf16x8 r;
  #pragma unroll
  for (int j = 0; j < 8; j++)
    r[j] = f2bfb(bfb2f(a[j]) + bfb2f(v1[j]) + bfb2f(v2[j]) + bfb2f(v3[j]));
  *reinterpret_cast<bf16x8*>(dst) = r;
}

// ---------------- fallback reduce --------------------------------------------
__global__ __launch_bounds__(256) void reduce3_kernel(bf16* __restrict__ dst,
    const bf16* __restrict__ p1, const bf16* __restrict__ p2,
    const bf16* __restrict__ p3) {
  int i = (blockIdx.x * 256 + threadIdx.x) * 8;
  bf16x8 a  = *reinterpret_cast<const bf16x8*>(dst + i);
  bf16x8 v1 = *reinterpret_cast<const bf16x8*>(p1 + i);
  bf16x8 v2 = *reinterpret_cast<const bf16x8*>(p2 + i);
  bf16x8 v3 = *reinterpret_cast<const bf16x8*>(p3 + i);
  bf16x8 r;
  #pragma unroll
  for (int j = 0; j < 8; j++)
    r[j] = f2bfb(bfb2f(a[j]) + bfb2f(v1[j]) + bfb2f(v2[j]) + bfb2f(v3[j]));
  *reinterpret_cast<bf16x8*>(dst + i) = r;
}

extern "C" void kernel_launch(void* const* d_in, const int* in_sizes, int n_in,
                              void* d_out, int out_size, void* d_ws, size_t ws_size,
                              hipStream_t stream) {
  const float* x     = (const float*)d_in[0];
  const float* gamma = (const float*)d_in[1];
  const float* beta  = (const float*)d_in[2];
  const float* wq    = (const float*)d_in[3];
  const float* bq    = (const float*)d_in[4];
  const float* wk    = (const float*)d_in[5];
  const float* bk    = (const float*)d_in[6];
  const float* wv    = (const float*)d_in[7];
  const float* bv    = (const float*)d_in[8];
  const float* wp    = (const float*)d_in[9];
  const float* bp    = (const float*)d_in[10];
  float* out = (float*)d_out;

  char* w = (char*)d_ws;
  size_t off = 0;
  float* pstats = (float*)(w + off);   off += 4096;
  float* bqk    = (float*)(w + off);   off += 4096;
  float* rspart = (float*)(w + off);   off += (size_t)2 * 4096 * 64 * 4;
  bf16* wqkb = (bf16*)(w + off);       off += (size_t)1024 * 512 * 2;
  bf16* wvb  = (bf16*)(w + off);       off += (size_t)512 * 512 * 2;
  bf16* wpb  = (bf16*)(w + off);       off += (size_t)512 * 512 * 2;
  bf16* h    = (bf16*)(w + off);       off += (size_t)2 * NPX * CCH * 2;
  bf16* qk   = (bf16*)(w + off);       off += (size_t)2 * NPX * 1024 * 2;
  bf16* v    = (bf16*)(w + off);       off += (size_t)2 * NPX * CCH * 2;
  bf16* o    = (bf16*)(w + off);       off += (size_t)2 * NPX * CCH * 2;
  bf16* S    = (bf16*)(w + off);
  size_t need_big = off + (size_t)2 * NPX * NPX * 2;
  const bool big = ws_size >= need_big;

  const long long sBN = (long long)NPX * CCH;
  const long long sQK = (long long)NPX * 1024;
  const long long sS  = (long long)NPX * NPX;
  const float scale = 0.04419417382415922f;

  prep_kernel<<<1536, 256, 0, stream>>>(wq, wk, wv, wp, bq, bk, x, wqkb, bqk, pstats);
  gn_apply_kernel<<<dim3(8, 64, 2), 256, 0, stream>>>(x, pstats, gamma, beta, h);

  GemmP pqkv = {h, wqkb, qk, nullptr, bqk, nullptr, nullptr,
                1.f, 512, 512, 512, 1024, sBN, 0, sQK, 0, 32, 8, 1};
  GemmP pv   = {wvb, h, v, bv, nullptr, nullptr, nullptr,
                1.f, 512, 512, 512, 4096, 0, sBN, sBN, 0, 4, 32, 1};
  gemm_any_kernel<<<768, 256, 0, stream>>>(pqkv, pv, 512);

  if (big) {
    qk8_kernel<<<512, 512, 0, stream>>>(qk, S, rspart, scale);
    Ptr8 slots{{o, h, qk, qk + sBN, o + sBN, h + sBN, qk + 2 * sBN, qk + 3 * sBN}};
    pv8_kernel<<<256, 512, 0, stream>>>(S, v, rspart, slots);
    reduce3x2_kernel<<<2048, 256, 0, stream>>>(o, h, qk);
  } else {
    for (int b = 0; b < 2; b++) {
      GemmP ps = {qk + b * sQK, qk + b * sQK + 512, S, nullptr, nullptr, nullptr,
                  rspart + ((size_t)b << 18),
                  scale, 512, 1024, 1024, 4096, 0, 0, 0, 0, 32, 32, 2};
      gemm_any_kernel<<<1024, 256, 0, stream>>>(ps, ps, 1024);
      Ptr8 slots{{o + b * sBN, h, h + sBN, (bf16*)out, nullptr, nullptr, nullptr, nullptr}};
      pv_split_kernel<<<dim3(32, 4, 4), 256, 0, stream>>>(S, v + b * sBN,
          rspart + ((size_t)b << 18), 0, 0, slots, 1);
      reduce3_kernel<<<1024, 256, 0, stream>>>(o + b * sBN, h, h + sBN, (bf16*)out);
    }
  }

  GemmP po = {wpb, o, out, bp, nullptr, x, nullptr,
              1.f, 512, 512, 512, 4096, 0, sBN, sBN, sBN, 4, 32, 0};
  gemm_any_kernel<<<256, 256, 0, stream>>>(po, po, 256);
}